// Round 1
// baseline (5987.316 us; speedup 1.0000x reference)
//
#include <hip/hip_runtime.h>
#include <hip/hip_bf16.h>

// Problem constants (shapes fixed by reference; N's derived from in_sizes)
#define R_SUP 5
#define D_IN 128
#define O_OUT 64

// ---------------------------------------------------------------------------
// cumsum over relation axis for both weight tensors. i indexes (d,o) flat.
__global__ __launch_bounds__(256) void cumsum_w(
    const float* __restrict__ wu, const float* __restrict__ wv,
    float* __restrict__ wcu, float* __restrict__ wcv) {
  int i = blockIdx.x * 256 + threadIdx.x;
  if (i >= D_IN * O_OUT) return;
  float su = 0.f, sv = 0.f;
#pragma unroll
  for (int r = 0; r < R_SUP; ++r) {
    su += wu[r * D_IN * O_OUT + i];
    sv += wv[r * D_IN * O_OUT + i];
    wcu[r * D_IN * O_OUT + i] = su;
    wcv[r * D_IN * O_OUT + i] = sv;
  }
}

// ---------------------------------------------------------------------------
// zero-fill (d_out is poisoned 0xAA before every timed call)
__global__ __launch_bounds__(256) void zero_f32(float* __restrict__ p, int n4) {
  int i = blockIdx.x * 256 + threadIdx.x;
  int stride = gridDim.x * 256;
  float4 z = make_float4(0.f, 0.f, 0.f, 0.f);
  for (; i < n4; i += stride) ((float4*)p)[i] = z;
}

// ---------------------------------------------------------------------------
// GEMM: out[n][o] = sum_d x[n][d] * w[d][o], tile 64 rows x 64 cols, D=128.
// LDS: x transposed [d][row] (padded) + full W [d][o]. fp32 vector FMA.
__global__ __launch_bounds__(256) void gemm64(
    const float* __restrict__ x, const float* __restrict__ w,
    float* __restrict__ out, int N) {
  __shared__ float sXT[D_IN][68];      // [d][row], 68 = 64 rows + pad (16B-aligned rows)
  __shared__ float sW[D_IN][O_OUT];    // [d][o]
  const int tid = threadIdx.x;
  const int row0 = blockIdx.x * 64;

  // stage W: 128*64 floats = 2048 float4
  for (int i = tid; i < 2048; i += 256) {
    int d = i >> 4;        // 16 float4 per d-row
    int o4 = i & 15;
    ((float4*)&sW[d][0])[o4] = ((const float4*)w)[i];
  }
  // stage X transposed: 64 rows * 128 d = 2048 float4 (along d)
  for (int i = tid; i < 2048; i += 256) {
    int rl = i >> 5;       // 32 float4 per row
    int d4 = i & 31;
    int row = row0 + rl;
    float4 xv = make_float4(0.f, 0.f, 0.f, 0.f);
    if (row < N) xv = ((const float4*)x)[row * 32 + d4];
    sXT[d4 * 4 + 0][rl] = xv.x;
    sXT[d4 * 4 + 1][rl] = xv.y;
    sXT[d4 * 4 + 2][rl] = xv.z;
    sXT[d4 * 4 + 3][rl] = xv.w;
  }
  __syncthreads();

  const int col4 = (tid & 15) * 4;   // consecutive tids -> consecutive cols (coalesced store)
  const int row4 = (tid >> 4) * 4;
  float acc[4][4] = {};
#pragma unroll 8
  for (int d = 0; d < D_IN; ++d) {
    float4 xv = *(const float4*)&sXT[d][row4];
    float4 wv = *(const float4*)&sW[d][col4];
    acc[0][0] += xv.x * wv.x; acc[0][1] += xv.x * wv.y; acc[0][2] += xv.x * wv.z; acc[0][3] += xv.x * wv.w;
    acc[1][0] += xv.y * wv.x; acc[1][1] += xv.y * wv.y; acc[1][2] += xv.y * wv.z; acc[1][3] += xv.y * wv.w;
    acc[2][0] += xv.z * wv.x; acc[2][1] += xv.z * wv.y; acc[2][2] += xv.z * wv.z; acc[2][3] += xv.z * wv.w;
    acc[3][0] += xv.w * wv.x; acc[3][1] += xv.w * wv.y; acc[3][2] += xv.w * wv.z; acc[3][3] += xv.w * wv.w;
  }
#pragma unroll
  for (int i = 0; i < 4; ++i) {
    int row = row0 + row4 + i;
    if (row < N)
      *(float4*)&out[row * O_OUT + col4] =
          make_float4(acc[i][0], acc[i][1], acc[i][2], acc[i][3]);
  }
}

// ---------------------------------------------------------------------------
// SpMM push: z[dst[e]] += vals[e] * tmp[src[e]], 16 threads per edge (4 floats each)
__global__ __launch_bounds__(256) void spmm_push(
    const int* __restrict__ dst, const int* __restrict__ src,
    const float* __restrict__ vals, const float* __restrict__ tmp,
    float* __restrict__ z, int E) {
  int t = blockIdx.x * 256 + threadIdx.x;
  int e = t >> 4;
  int lane = t & 15;
  if (e >= E) return;
  int d_ = dst[e];
  int s_ = src[e];
  float v = vals[e];
  float4 f = ((const float4*)tmp)[s_ * 16 + lane];
  float* zp = z + (size_t)d_ * O_OUT + lane * 4;
  atomicAdd(zp + 0, v * f.x);
  atomicAdd(zp + 1, v * f.y);
  atomicAdd(zp + 2, v * f.z);
  atomicAdd(zp + 3, v * f.w);
}

// ---------------------------------------------------------------------------
__global__ __launch_bounds__(256) void relu_f32(float* __restrict__ p, int n4) {
  int i = blockIdx.x * 256 + threadIdx.x;
  int stride = gridDim.x * 256;
  for (; i < n4; i += stride) {
    float4 v = ((float4*)p)[i];
    v.x = v.x > 0.f ? v.x : 0.f;
    v.y = v.y > 0.f ? v.y : 0.f;
    v.z = v.z > 0.f ? v.z : 0.f;
    v.w = v.w > 0.f ? v.w : 0.f;
    ((float4*)p)[i] = v;
  }
}

// ---------------------------------------------------------------------------
extern "C" void kernel_launch(void* const* d_in, const int* in_sizes, int n_in,
                              void* d_out, int out_size, void* d_ws, size_t ws_size,
                              hipStream_t stream) {
  const float* x_u      = (const float*)d_in[0];
  const float* x_v      = (const float*)d_in[1];
  const int*   sup_rows = (const int*)d_in[2];
  const int*   sup_cols = (const int*)d_in[3];
  const float* sup_vals = (const float*)d_in[4];
  const float* wu       = (const float*)d_in[5];
  const float* wv       = (const float*)d_in[6];

  const int NU = in_sizes[0] / D_IN;
  const int NV = in_sizes[1] / D_IN;
  const int E  = in_sizes[2] / R_SUP;

  float* out  = (float*)d_out;
  float* z_u  = out;                         // [NU, 64]
  float* z_v  = out + (size_t)NU * O_OUT;    // [NV, 64]

  // workspace layout (floats)
  float* wcu = (float*)d_ws;                                   // R*D*O
  float* wcv = wcu + R_SUP * D_IN * O_OUT;                     // R*D*O
  float* tmp = wcv + R_SUP * D_IN * O_OUT;                     // max(NU,NV)*O

  const int n4_out = out_size / 4;
  zero_f32<<<1024, 256, 0, stream>>>(out, n4_out);
  cumsum_w<<<(D_IN * O_OUT + 255) / 256, 256, 0, stream>>>(wu, wv, wcu, wcv);

  const int gemm_blocks_u = (NU + 63) / 64;
  const int gemm_blocks_v = (NV + 63) / 64;
  const int spmm_blocks   = (E * 16 + 255) / 256;

  for (int r = 0; r < R_SUP; ++r) {
    const int* rws = sup_rows + (size_t)r * E;
    const int* cls = sup_cols + (size_t)r * E;
    const float* vls = sup_vals + (size_t)r * E;
    // z_u += S_r @ (x_v @ Wv_cum[r])
    gemm64<<<gemm_blocks_v, 256, 0, stream>>>(x_v, wcv + r * D_IN * O_OUT, tmp, NV);
    spmm_push<<<spmm_blocks, 256, 0, stream>>>(rws, cls, vls, tmp, z_u, E);
    // z_v += S_r^T @ (x_u @ Wu_cum[r])
    gemm64<<<gemm_blocks_u, 256, 0, stream>>>(x_u, wcu + r * D_IN * O_OUT, tmp, NU);
    spmm_push<<<spmm_blocks, 256, 0, stream>>>(cls, rws, vls, tmp, z_v, E);
  }

  relu_f32<<<1024, 256, 0, stream>>>(out, n4_out);
}

// Round 2
// 1791.270 us; speedup vs baseline: 3.3425x; 3.3425x over previous
//
#include <hip/hip_runtime.h>
#include <hip/hip_bf16.h>

// Problem constants (shapes fixed by reference; N's derived from in_sizes)
#define R_SUP 5
#define D_IN 128
#define O_OUT 64

// ---------------------------------------------------------------------------
// cumsum over relation axis for both weight tensors. i indexes (d,o) flat.
__global__ __launch_bounds__(256) void cumsum_w(
    const float* __restrict__ wu, const float* __restrict__ wv,
    float* __restrict__ wcu, float* __restrict__ wcv) {
  int i = blockIdx.x * 256 + threadIdx.x;
  if (i >= D_IN * O_OUT) return;
  float su = 0.f, sv = 0.f;
#pragma unroll
  for (int r = 0; r < R_SUP; ++r) {
    su += wu[r * D_IN * O_OUT + i];
    sv += wv[r * D_IN * O_OUT + i];
    wcu[r * D_IN * O_OUT + i] = su;
    wcv[r * D_IN * O_OUT + i] = sv;
  }
}

// ---------------------------------------------------------------------------
__global__ __launch_bounds__(256) void zero_f32(float* __restrict__ p, int n4) {
  int i = blockIdx.x * 256 + threadIdx.x;
  int stride = gridDim.x * 256;
  float4 z = make_float4(0.f, 0.f, 0.f, 0.f);
  for (; i < n4; i += stride) ((float4*)p)[i] = z;
}

__global__ __launch_bounds__(256) void zero_i32(int* __restrict__ p, int n) {
  int i = blockIdx.x * 256 + threadIdx.x;
  int stride = gridDim.x * 256;
  for (; i < n; i += stride) p[i] = 0;
}

__global__ __launch_bounds__(256) void copy_i32(const int* __restrict__ a,
                                               int* __restrict__ b, int n) {
  int i = blockIdx.x * 256 + threadIdx.x;
  int stride = gridDim.x * 256;
  for (; i < n; i += stride) b[i] = a[i];
}

// ---------------------------------------------------------------------------
// GEMM: out[n][o] = sum_d x[n][d] * w[d][o], tile 64 rows x 64 cols, D=128.
__global__ __launch_bounds__(256) void gemm64(
    const float* __restrict__ x, const float* __restrict__ w,
    float* __restrict__ out, int N) {
  __shared__ float sXT[D_IN][68];
  __shared__ float sW[D_IN][O_OUT];
  const int tid = threadIdx.x;
  const int row0 = blockIdx.x * 64;

  for (int i = tid; i < 2048; i += 256) {
    int d = i >> 4;
    int o4 = i & 15;
    ((float4*)&sW[d][0])[o4] = ((const float4*)w)[i];
  }
  for (int i = tid; i < 2048; i += 256) {
    int rl = i >> 5;
    int d4 = i & 31;
    int row = row0 + rl;
    float4 xv = make_float4(0.f, 0.f, 0.f, 0.f);
    if (row < N) xv = ((const float4*)x)[row * 32 + d4];
    sXT[d4 * 4 + 0][rl] = xv.x;
    sXT[d4 * 4 + 1][rl] = xv.y;
    sXT[d4 * 4 + 2][rl] = xv.z;
    sXT[d4 * 4 + 3][rl] = xv.w;
  }
  __syncthreads();

  const int col4 = (tid & 15) * 4;
  const int row4 = (tid >> 4) * 4;
  float acc[4][4] = {};
#pragma unroll 8
  for (int d = 0; d < D_IN; ++d) {
    float4 xv = *(const float4*)&sXT[d][row4];
    float4 wv = *(const float4*)&sW[d][col4];
    acc[0][0] += xv.x * wv.x; acc[0][1] += xv.x * wv.y; acc[0][2] += xv.x * wv.z; acc[0][3] += xv.x * wv.w;
    acc[1][0] += xv.y * wv.x; acc[1][1] += xv.y * wv.y; acc[1][2] += xv.y * wv.z; acc[1][3] += xv.y * wv.w;
    acc[2][0] += xv.z * wv.x; acc[2][1] += xv.z * wv.y; acc[2][2] += xv.z * wv.z; acc[2][3] += xv.z * wv.w;
    acc[3][0] += xv.w * wv.x; acc[3][1] += xv.w * wv.y; acc[3][2] += xv.w * wv.z; acc[3][3] += xv.w * wv.w;
  }
#pragma unroll
  for (int i = 0; i < 4; ++i) {
    int row = row0 + row4 + i;
    if (row < N)
      *(float4*)&out[row * O_OUT + col4] =
          make_float4(acc[i][0], acc[i][1], acc[i][2], acc[i][3]);
  }
}

// ---------------------------------------------------------------------------
// CSR build: histogram over destination ids (all 5 relations in one pass)
__global__ __launch_bounds__(256) void hist_edges(
    const int* __restrict__ dsts, int* __restrict__ cnt, int nE) {
  int i = blockIdx.x * 256 + threadIdx.x;
  if (i >= nE) return;
  atomicAdd(&cnt[dsts[i]], 1);
}

// single-workgroup exclusive scan: row_ptr[0..n], row_ptr[i+1]=row_ptr[i]+cnt[i]
__global__ __launch_bounds__(1024) void scan_rowptr(
    const int* __restrict__ cnt, int* __restrict__ row_ptr, int n) {
  __shared__ int part[1024];
  __shared__ int excl[1025];
  const int t = threadIdx.x;
  const int chunk = (n + 1023) >> 10;
  const int lo = t * chunk;
  const int hi = min(lo + chunk, n);
  int s = 0;
  for (int i = lo; i < hi; ++i) s += cnt[i];
  part[t] = s;
  __syncthreads();
  if (t == 0) {
    int run = 0;
    for (int i = 0; i < 1024; ++i) { excl[i] = run; run += part[i]; }
    excl[1024] = run;
  }
  __syncthreads();
  int base = excl[t];
  for (int i = lo; i < hi; ++i) { row_ptr[i] = base; base += cnt[i]; }
  if (t == 0) row_ptr[n] = excl[1024];
}

// scatter edges into dst-sorted arrays; r packed into bits [20..] of entry
// (requires src < 2^20; here src < 100000)
__global__ __launch_bounds__(256) void scatter_edges(
    const int* __restrict__ dsts, const int* __restrict__ srcs,
    const float* __restrict__ vals, int* __restrict__ cursor,
    int* __restrict__ entries, float* __restrict__ evals, int nE, int E) {
  int i = blockIdx.x * 256 + threadIdx.x;
  if (i >= nE) return;
  int dst = dsts[i];
  int src = srcs[i];
  int r = i / E;
  int pos = atomicAdd(&cursor[dst], 1);
  entries[pos] = (r << 20) | src;
  evals[pos] = vals[i];
}

// ---------------------------------------------------------------------------
// Pull SpMM fused over relations + ReLU. 16 lanes per destination row.
// tmp5: [R][Nmax][64] fp32; strideR = Nmax*64.
__global__ __launch_bounds__(256) void spmm_pull_fused(
    const int* __restrict__ row_ptr, const int* __restrict__ entries,
    const float* __restrict__ evals, const float* __restrict__ tmp5,
    size_t strideR, float* __restrict__ z, int Ndst) {
  int g = (blockIdx.x * 256 + threadIdx.x) >> 4;
  int lane = threadIdx.x & 15;
  if (g >= Ndst) return;
  int s = row_ptr[g];
  int e = row_ptr[g + 1];
  float4 acc = make_float4(0.f, 0.f, 0.f, 0.f);
  for (int i = s; i < e; ++i) {
    int pk = entries[i];
    float v = evals[i];
    int r = pk >> 20;
    int src = pk & 0xFFFFF;
    const float4* row = (const float4*)(tmp5 + (size_t)r * strideR + (size_t)src * O_OUT);
    float4 f = row[lane];
    acc.x += v * f.x;
    acc.y += v * f.y;
    acc.z += v * f.z;
    acc.w += v * f.w;
  }
  acc.x = acc.x > 0.f ? acc.x : 0.f;
  acc.y = acc.y > 0.f ? acc.y : 0.f;
  acc.z = acc.z > 0.f ? acc.z : 0.f;
  acc.w = acc.w > 0.f ? acc.w : 0.f;
  ((float4*)(z + (size_t)g * O_OUT))[lane] = acc;
}

// ---------------------------------------------------------------------------
// Fallback (round-1 push path) kernels
__global__ __launch_bounds__(256) void spmm_push(
    const int* __restrict__ dst, const int* __restrict__ src,
    const float* __restrict__ vals, const float* __restrict__ tmp,
    float* __restrict__ z, int E) {
  int t = blockIdx.x * 256 + threadIdx.x;
  int e = t >> 4;
  int lane = t & 15;
  if (e >= E) return;
  int d_ = dst[e];
  int s_ = src[e];
  float v = vals[e];
  float4 f = ((const float4*)tmp)[s_ * 16 + lane];
  float* zp = z + (size_t)d_ * O_OUT + lane * 4;
  atomicAdd(zp + 0, v * f.x);
  atomicAdd(zp + 1, v * f.y);
  atomicAdd(zp + 2, v * f.z);
  atomicAdd(zp + 3, v * f.w);
}

__global__ __launch_bounds__(256) void relu_f32(float* __restrict__ p, int n4) {
  int i = blockIdx.x * 256 + threadIdx.x;
  int stride = gridDim.x * 256;
  for (; i < n4; i += stride) {
    float4 v = ((float4*)p)[i];
    v.x = v.x > 0.f ? v.x : 0.f;
    v.y = v.y > 0.f ? v.y : 0.f;
    v.z = v.z > 0.f ? v.z : 0.f;
    v.w = v.w > 0.f ? v.w : 0.f;
    ((float4*)p)[i] = v;
  }
}

// ---------------------------------------------------------------------------
extern "C" void kernel_launch(void* const* d_in, const int* in_sizes, int n_in,
                              void* d_out, int out_size, void* d_ws, size_t ws_size,
                              hipStream_t stream) {
  const float* x_u      = (const float*)d_in[0];
  const float* x_v      = (const float*)d_in[1];
  const int*   sup_rows = (const int*)d_in[2];
  const int*   sup_cols = (const int*)d_in[3];
  const float* sup_vals = (const float*)d_in[4];
  const float* wu       = (const float*)d_in[5];
  const float* wv       = (const float*)d_in[6];

  const int NU = in_sizes[0] / D_IN;
  const int NV = in_sizes[1] / D_IN;
  const int E  = in_sizes[2] / R_SUP;
  const int Nmax = NU > NV ? NU : NV;
  const int nE5 = R_SUP * E;

  float* out = (float*)d_out;
  float* z_u = out;
  float* z_v = out + (size_t)NU * O_OUT;

  const int WDO = R_SUP * D_IN * O_OUT;  // 40960

  // --- Path A workspace layout (floats/ints), 16B-aligned segments ---
  // [wcu | wcv | tmp5 (5*Nmax*64) | row_ptr (Nmax+16) | cursor (Nmax+16) |
  //  entries (5E) | evals (5E)]
  const size_t npad = (size_t)Nmax + 16;
  const size_t needA =
      ((size_t)2 * WDO + (size_t)R_SUP * Nmax * O_OUT + 2 * npad + (size_t)2 * nE5) * 4;

  float* wcu = (float*)d_ws;
  float* wcv = wcu + WDO;

  cumsum_w<<<(D_IN * O_OUT + 255) / 256, 256, 0, stream>>>(wu, wv, wcu, wcv);

  if (ws_size >= needA) {
    float* tmp5    = wcv + WDO;
    int*   row_ptr = (int*)(tmp5 + (size_t)R_SUP * Nmax * O_OUT);
    int*   cursor  = row_ptr + npad;
    int*   entries = cursor + npad;
    float* evals   = (float*)(entries + nE5);
    const size_t strideR = (size_t)Nmax * O_OUT;

    const int hist_blocks = (nE5 + 255) / 256;

    // ---- direction u: z_u = relu(sum_r S_r @ (x_v @ Wv_cum[r])) ----
    for (int r = 0; r < R_SUP; ++r)
      gemm64<<<(NV + 63) / 64, 256, 0, stream>>>(
          x_v, wcv + r * D_IN * O_OUT, tmp5 + r * strideR, NV);
    zero_i32<<<(NU + 255) / 256, 256, 0, stream>>>(cursor, NU);
    hist_edges<<<hist_blocks, 256, 0, stream>>>(sup_rows, cursor, nE5);
    scan_rowptr<<<1, 1024, 0, stream>>>(cursor, row_ptr, NU);
    copy_i32<<<(NU + 255) / 256, 256, 0, stream>>>(row_ptr, cursor, NU);
    scatter_edges<<<hist_blocks, 256, 0, stream>>>(
        sup_rows, sup_cols, sup_vals, cursor, entries, evals, nE5, E);
    spmm_pull_fused<<<(NU * 16 + 255) / 256, 256, 0, stream>>>(
        row_ptr, entries, evals, tmp5, strideR, z_u, NU);

    // ---- direction v: z_v = relu(sum_r S_r^T @ (x_u @ Wu_cum[r])) ----
    for (int r = 0; r < R_SUP; ++r)
      gemm64<<<(NU + 63) / 64, 256, 0, stream>>>(
          x_u, wcu + r * D_IN * O_OUT, tmp5 + r * strideR, NU);
    zero_i32<<<(NV + 255) / 256, 256, 0, stream>>>(cursor, NV);
    hist_edges<<<hist_blocks, 256, 0, stream>>>(sup_cols, cursor, nE5);
    scan_rowptr<<<1, 1024, 0, stream>>>(cursor, row_ptr, NV);
    copy_i32<<<(NV + 255) / 256, 256, 0, stream>>>(row_ptr, cursor, NV);
    scatter_edges<<<hist_blocks, 256, 0, stream>>>(
        sup_cols, sup_rows, sup_vals, cursor, entries, evals, nE5, E);
    spmm_pull_fused<<<(NV * 16 + 255) / 256, 256, 0, stream>>>(
        row_ptr, entries, evals, tmp5, strideR, z_v, NV);
  } else {
    // ---- fallback: round-1 push-atomic path (ws too small for Path A) ----
    float* tmp = wcv + WDO;
    const int n4_out = out_size / 4;
    zero_f32<<<1024, 256, 0, stream>>>(out, n4_out);
    const int spmm_blocks = (E * 16 + 255) / 256;
    for (int r = 0; r < R_SUP; ++r) {
      const int* rws = sup_rows + (size_t)r * E;
      const int* cls = sup_cols + (size_t)r * E;
      const float* vls = sup_vals + (size_t)r * E;
      gemm64<<<(NV + 63) / 64, 256, 0, stream>>>(x_v, wcv + r * D_IN * O_OUT, tmp, NV);
      spmm_push<<<spmm_blocks, 256, 0, stream>>>(rws, cls, vls, tmp, z_u, E);
      gemm64<<<(NU + 63) / 64, 256, 0, stream>>>(x_u, wcu + r * D_IN * O_OUT, tmp, NU);
      spmm_push<<<spmm_blocks, 256, 0, stream>>>(cls, rws, vls, tmp, z_v, E);
    }
    relu_f32<<<1024, 256, 0, stream>>>(out, n4_out);
  }
}

// Round 3
// 1690.101 us; speedup vs baseline: 3.5426x; 1.0599x over previous
//
#include <hip/hip_runtime.h>
#include <hip/hip_bf16.h>

// Problem constants (shapes fixed by reference; N's derived from in_sizes)
#define R_SUP 5
#define D_IN 128
#define O_OUT 64

// fp32 -> bf16 round-to-nearest-even (bit-exact with numpy/JAX RNE)
__device__ __forceinline__ unsigned short f2bf(float f) {
  union { float f; unsigned int u; } c; c.f = f;
  unsigned int u = c.u;
  return (unsigned short)((u + 0x7FFFu + ((u >> 16) & 1u)) >> 16);
}
__device__ __forceinline__ float bf2f(unsigned short h) {
  return __uint_as_float(((unsigned int)h) << 16);
}

// ---------------------------------------------------------------------------
// cumsum over relation axis for both weight tensors. i indexes (d,o) flat.
__global__ __launch_bounds__(256) void cumsum_w(
    const float* __restrict__ wu, const float* __restrict__ wv,
    float* __restrict__ wcu, float* __restrict__ wcv) {
  int i = blockIdx.x * 256 + threadIdx.x;
  if (i >= D_IN * O_OUT) return;
  float su = 0.f, sv = 0.f;
#pragma unroll
  for (int r = 0; r < R_SUP; ++r) {
    su += wu[r * D_IN * O_OUT + i];
    sv += wv[r * D_IN * O_OUT + i];
    wcu[r * D_IN * O_OUT + i] = su;
    wcv[r * D_IN * O_OUT + i] = sv;
  }
}

// ---------------------------------------------------------------------------
__global__ __launch_bounds__(256) void zero_f32(float* __restrict__ p, int n4) {
  int i = blockIdx.x * 256 + threadIdx.x;
  int stride = gridDim.x * 256;
  float4 z = make_float4(0.f, 0.f, 0.f, 0.f);
  for (; i < n4; i += stride) ((float4*)p)[i] = z;
}

__global__ __launch_bounds__(256) void zero_i32(int* __restrict__ p, int n) {
  int i = blockIdx.x * 256 + threadIdx.x;
  int stride = gridDim.x * 256;
  for (; i < n; i += stride) p[i] = 0;
}

// ---------------------------------------------------------------------------
// Batched GEMM: for r in 0..4: tmp5[r][n][o] = bf16( sum_d x[n][d]*wc[r][d][o] )
// x-tile (64 rows) staged in LDS once, reused across all 5 relations.
__global__ __launch_bounds__(256) void gemm5_bf16(
    const float* __restrict__ x, const float* __restrict__ wc,
    unsigned short* __restrict__ tmp5, size_t strideR, int N) {
  __shared__ float sXT[D_IN][68];      // [d][row], padded
  __shared__ float sW[D_IN][O_OUT];    // [d][o]
  const int tid = threadIdx.x;
  const int row0 = blockIdx.x * 64;

  // stage X transposed once: 64 rows * 128 d
  for (int i = tid; i < 2048; i += 256) {
    int rl = i >> 5;
    int d4 = i & 31;
    int row = row0 + rl;
    float4 xv = make_float4(0.f, 0.f, 0.f, 0.f);
    if (row < N) xv = ((const float4*)x)[(size_t)row * 32 + d4];
    sXT[d4 * 4 + 0][rl] = xv.x;
    sXT[d4 * 4 + 1][rl] = xv.y;
    sXT[d4 * 4 + 2][rl] = xv.z;
    sXT[d4 * 4 + 3][rl] = xv.w;
  }

  const int col4 = (tid & 15) * 4;
  const int row4 = (tid >> 4) * 4;

  for (int r = 0; r < R_SUP; ++r) {
    __syncthreads();  // sXT ready (r=0); sW free of prior readers (r>0)
    const float* wr = wc + r * D_IN * O_OUT;
    for (int i = tid; i < 2048; i += 256) {
      int d = i >> 4;
      int o4 = i & 15;
      ((float4*)&sW[d][0])[o4] = ((const float4*)wr)[i];
    }
    __syncthreads();

    float acc[4][4] = {};
#pragma unroll 8
    for (int d = 0; d < D_IN; ++d) {
      float4 xv = *(const float4*)&sXT[d][row4];
      float4 wv = *(const float4*)&sW[d][col4];
      acc[0][0] += xv.x * wv.x; acc[0][1] += xv.x * wv.y; acc[0][2] += xv.x * wv.z; acc[0][3] += xv.x * wv.w;
      acc[1][0] += xv.y * wv.x; acc[1][1] += xv.y * wv.y; acc[1][2] += xv.y * wv.z; acc[1][3] += xv.y * wv.w;
      acc[2][0] += xv.z * wv.x; acc[2][1] += xv.z * wv.y; acc[2][2] += xv.z * wv.z; acc[2][3] += xv.z * wv.w;
      acc[3][0] += xv.w * wv.x; acc[3][1] += xv.w * wv.y; acc[3][2] += xv.w * wv.z; acc[3][3] += xv.w * wv.w;
    }
#pragma unroll
    for (int i = 0; i < 4; ++i) {
      int row = row0 + row4 + i;
      if (row < N) {
        ushort4 h;
        h.x = f2bf(acc[i][0]);
        h.y = f2bf(acc[i][1]);
        h.z = f2bf(acc[i][2]);
        h.w = f2bf(acc[i][3]);
        *(ushort4*)&tmp5[r * strideR + (size_t)row * O_OUT + col4] = h;
      }
    }
  }
}

// ---------------------------------------------------------------------------
// Histogram for both directions in one pass over all R*E edges.
__global__ __launch_bounds__(256) void hist_both(
    const int* __restrict__ rows, const int* __restrict__ cols,
    int* __restrict__ cnt_u, int* __restrict__ cnt_v, int nE) {
  int i = blockIdx.x * 256 + threadIdx.x;
  if (i >= nE) return;
  atomicAdd(&cnt_u[rows[i]], 1);
  atomicAdd(&cnt_v[cols[i]], 1);
}

// Exclusive scan for both directions (block 0 -> u, block 1 -> v).
// Writes row_ptr AND rewrites cnt in place as the scatter cursor (aliasing is
// race-free: each element owned by one thread; phase-1 reads complete before
// the barrier, phase-2 writes after).
__global__ __launch_bounds__(1024) void scan2(
    int* __restrict__ cnt_u, int* __restrict__ cnt_v,
    int* __restrict__ rp_u, int* __restrict__ rp_v, int nu, int nv) {
  int* cnt = blockIdx.x ? cnt_v : cnt_u;
  int* rp  = blockIdx.x ? rp_v  : rp_u;
  int n    = blockIdx.x ? nv    : nu;
  __shared__ int part[1024];
  __shared__ int excl[1025];
  const int t = threadIdx.x;
  const int chunk = (n + 1023) >> 10;
  const int lo = min(t * chunk, n);
  const int hi = min(lo + chunk, n);
  int s = 0;
  for (int i = lo; i < hi; ++i) s += cnt[i];
  part[t] = s;
  __syncthreads();
  if (t == 0) {
    int run = 0;
    for (int i = 0; i < 1024; ++i) { excl[i] = run; run += part[i]; }
    excl[1024] = run;
  }
  __syncthreads();
  int base = excl[t];
  for (int i = lo; i < hi; ++i) {
    int c = cnt[i];
    rp[i] = base;
    cnt[i] = base;   // cursor for scatter
    base += c;
  }
  if (t == 0) rp[n] = excl[1024];
}

// Scatter both directions: one interleaved 8B payload per edge per direction.
__global__ __launch_bounds__(256) void scatter_both(
    const int* __restrict__ rows, const int* __restrict__ cols,
    const float* __restrict__ vals, int* __restrict__ cur_u,
    int* __restrict__ cur_v, int2* __restrict__ ep_u, int2* __restrict__ ep_v,
    int nE, int E) {
  int i = blockIdx.x * 256 + threadIdx.x;
  if (i >= nE) return;
  int rr = rows[i];
  int cc = cols[i];
  int vbits = __float_as_int(vals[i]);
  int tag = (i / E) << 20;
  int pu = atomicAdd(&cur_u[rr], 1);
  ep_u[pu] = make_int2(tag | cc, vbits);
  int pv = atomicAdd(&cur_v[cc], 1);
  ep_v[pv] = make_int2(tag | rr, vbits);
}

// ---------------------------------------------------------------------------
// Pull SpMM fused over relations + ReLU. 16 lanes per destination row.
// tmp5: [R][Nmax][64] bf16; strideR in elements.
__global__ __launch_bounds__(256) void spmm_pull_bf16(
    const int* __restrict__ rp, const int2* __restrict__ ep,
    const unsigned short* __restrict__ tmp5, size_t strideR,
    float* __restrict__ z, int Ndst) {
  int g = (blockIdx.x * 256 + threadIdx.x) >> 4;
  int lane = threadIdx.x & 15;
  if (g >= Ndst) return;
  int s = rp[g];
  int e = rp[g + 1];
  float4 acc = make_float4(0.f, 0.f, 0.f, 0.f);
  for (int i = s; i < e; ++i) {
    int2 pk = ep[i];
    float v = __int_as_float(pk.y);
    int r = pk.x >> 20;
    int src = pk.x & 0xFFFFF;
    const ushort4* row =
        (const ushort4*)(tmp5 + (size_t)r * strideR + (size_t)src * O_OUT);
    ushort4 h = row[lane];
    acc.x += v * bf2f(h.x);
    acc.y += v * bf2f(h.y);
    acc.z += v * bf2f(h.z);
    acc.w += v * bf2f(h.w);
  }
  acc.x = acc.x > 0.f ? acc.x : 0.f;
  acc.y = acc.y > 0.f ? acc.y : 0.f;
  acc.z = acc.z > 0.f ? acc.z : 0.f;
  acc.w = acc.w > 0.f ? acc.w : 0.f;
  ((float4*)(z + (size_t)g * O_OUT))[lane] = acc;
}

// ---------------------------------------------------------------------------
// Fallback (round-1 push path) kernels — only used if ws_size is tiny.
__global__ __launch_bounds__(256) void gemm64(
    const float* __restrict__ x, const float* __restrict__ w,
    float* __restrict__ out, int N) {
  __shared__ float sXT[D_IN][68];
  __shared__ float sW[D_IN][O_OUT];
  const int tid = threadIdx.x;
  const int row0 = blockIdx.x * 64;
  for (int i = tid; i < 2048; i += 256) {
    int d = i >> 4;
    int o4 = i & 15;
    ((float4*)&sW[d][0])[o4] = ((const float4*)w)[i];
  }
  for (int i = tid; i < 2048; i += 256) {
    int rl = i >> 5;
    int d4 = i & 31;
    int row = row0 + rl;
    float4 xv = make_float4(0.f, 0.f, 0.f, 0.f);
    if (row < N) xv = ((const float4*)x)[(size_t)row * 32 + d4];
    sXT[d4 * 4 + 0][rl] = xv.x;
    sXT[d4 * 4 + 1][rl] = xv.y;
    sXT[d4 * 4 + 2][rl] = xv.z;
    sXT[d4 * 4 + 3][rl] = xv.w;
  }
  __syncthreads();
  const int col4 = (tid & 15) * 4;
  const int row4 = (tid >> 4) * 4;
  float acc[4][4] = {};
#pragma unroll 8
  for (int d = 0; d < D_IN; ++d) {
    float4 xv = *(const float4*)&sXT[d][row4];
    float4 wv = *(const float4*)&sW[d][col4];
    acc[0][0] += xv.x * wv.x; acc[0][1] += xv.x * wv.y; acc[0][2] += xv.x * wv.z; acc[0][3] += xv.x * wv.w;
    acc[1][0] += xv.y * wv.x; acc[1][1] += xv.y * wv.y; acc[1][2] += xv.y * wv.z; acc[1][3] += xv.y * wv.w;
    acc[2][0] += xv.z * wv.x; acc[2][1] += xv.z * wv.y; acc[2][2] += xv.z * wv.z; acc[2][3] += xv.z * wv.w;
    acc[3][0] += xv.w * wv.x; acc[3][1] += xv.w * wv.y; acc[3][2] += xv.w * wv.z; acc[3][3] += xv.w * wv.w;
  }
#pragma unroll
  for (int i = 0; i < 4; ++i) {
    int row = row0 + row4 + i;
    if (row < N)
      *(float4*)&out[row * O_OUT + col4] =
          make_float4(acc[i][0], acc[i][1], acc[i][2], acc[i][3]);
  }
}

__global__ __launch_bounds__(256) void spmm_push(
    const int* __restrict__ dst, const int* __restrict__ src,
    const float* __restrict__ vals, const float* __restrict__ tmp,
    float* __restrict__ z, int E) {
  int t = blockIdx.x * 256 + threadIdx.x;
  int e = t >> 4;
  int lane = t & 15;
  if (e >= E) return;
  int d_ = dst[e];
  int s_ = src[e];
  float v = vals[e];
  float4 f = ((const float4*)tmp)[s_ * 16 + lane];
  float* zp = z + (size_t)d_ * O_OUT + lane * 4;
  atomicAdd(zp + 0, v * f.x);
  atomicAdd(zp + 1, v * f.y);
  atomicAdd(zp + 2, v * f.z);
  atomicAdd(zp + 3, v * f.w);
}

__global__ __launch_bounds__(256) void relu_f32(float* __restrict__ p, int n4) {
  int i = blockIdx.x * 256 + threadIdx.x;
  int stride = gridDim.x * 256;
  for (; i < n4; i += stride) {
    float4 v = ((float4*)p)[i];
    v.x = v.x > 0.f ? v.x : 0.f;
    v.y = v.y > 0.f ? v.y : 0.f;
    v.z = v.z > 0.f ? v.z : 0.f;
    v.w = v.w > 0.f ? v.w : 0.f;
    ((float4*)p)[i] = v;
  }
}

// ---------------------------------------------------------------------------
extern "C" void kernel_launch(void* const* d_in, const int* in_sizes, int n_in,
                              void* d_out, int out_size, void* d_ws, size_t ws_size,
                              hipStream_t stream) {
  const float* x_u      = (const float*)d_in[0];
  const float* x_v      = (const float*)d_in[1];
  const int*   sup_rows = (const int*)d_in[2];
  const int*   sup_cols = (const int*)d_in[3];
  const float* sup_vals = (const float*)d_in[4];
  const float* wu       = (const float*)d_in[5];
  const float* wv       = (const float*)d_in[6];

  const int NU = in_sizes[0] / D_IN;
  const int NV = in_sizes[1] / D_IN;
  const int E  = in_sizes[2] / R_SUP;
  const int Nmax = NU > NV ? NU : NV;
  const int nE5 = R_SUP * E;

  float* out = (float*)d_out;
  float* z_u = out;
  float* z_v = out + (size_t)NU * O_OUT;

  const int WDO = R_SUP * D_IN * O_OUT;  // 40960
  const size_t npad = (size_t)Nmax + 16;
  const size_t strideR = (size_t)Nmax * O_OUT;

  // --- Path A workspace layout (8B-aligned first) ---
  // [ep_u int2 | ep_v int2 | tmp5 ushort | wcu f | wcv f | cnt_u | cnt_v |
  //  rp_u | rp_v]
  const size_t needA = (size_t)nE5 * 16 + strideR * R_SUP * 2 +
                       (size_t)2 * WDO * 4 + 4 * npad * 4 + 256;

  if (ws_size >= needA) {
    int2* ep_u = (int2*)d_ws;
    int2* ep_v = ep_u + nE5;
    unsigned short* tmp5 = (unsigned short*)(ep_v + nE5);
    float* wcu = (float*)(tmp5 + strideR * R_SUP);
    float* wcv = wcu + WDO;
    int* cnt_u = (int*)(wcv + WDO);
    int* cnt_v = cnt_u + npad;
    int* rp_u  = cnt_v + npad;
    int* rp_v  = rp_u + npad;

    const int eb = (nE5 + 255) / 256;

    cumsum_w<<<(D_IN * O_OUT + 255) / 256, 256, 0, stream>>>(wu, wv, wcu, wcv);
    zero_i32<<<(2 * (int)npad + 255) / 256, 256, 0, stream>>>(cnt_u, 2 * (int)npad);
    hist_both<<<eb, 256, 0, stream>>>(sup_rows, sup_cols, cnt_u, cnt_v, nE5);
    scan2<<<2, 1024, 0, stream>>>(cnt_u, cnt_v, rp_u, rp_v, NU, NV);
    scatter_both<<<eb, 256, 0, stream>>>(sup_rows, sup_cols, sup_vals, cnt_u,
                                         cnt_v, ep_u, ep_v, nE5, E);

    // direction u: z_u = relu(sum_r S_r @ (x_v @ Wv_cum[r]))
    gemm5_bf16<<<(NV + 63) / 64, 256, 0, stream>>>(x_v, wcv, tmp5, strideR, NV);
    spmm_pull_bf16<<<(NU * 16 + 255) / 256, 256, 0, stream>>>(
        rp_u, ep_u, tmp5, strideR, z_u, NU);

    // direction v: z_v = relu(sum_r S_r^T @ (x_u @ Wu_cum[r]))
    gemm5_bf16<<<(NU + 63) / 64, 256, 0, stream>>>(x_u, wcu, tmp5, strideR, NU);
    spmm_pull_bf16<<<(NV * 16 + 255) / 256, 256, 0, stream>>>(
        rp_v, ep_v, tmp5, strideR, z_v, NV);
  } else {
    // ---- fallback: push-atomic path ----
    float* wcu = (float*)d_ws;
    float* wcv = wcu + WDO;
    float* tmp = wcv + WDO;
    const int n4_out = out_size / 4;
    cumsum_w<<<(D_IN * O_OUT + 255) / 256, 256, 0, stream>>>(wu, wv, wcu, wcv);
    zero_f32<<<1024, 256, 0, stream>>>(out, n4_out);
    const int spmm_blocks = (E * 16 + 255) / 256;
    for (int r = 0; r < R_SUP; ++r) {
      const int* rws = sup_rows + (size_t)r * E;
      const int* cls = sup_cols + (size_t)r * E;
      const float* vls = sup_vals + (size_t)r * E;
      gemm64<<<(NV + 63) / 64, 256, 0, stream>>>(x_v, wcv + r * D_IN * O_OUT, tmp, NV);
      spmm_push<<<spmm_blocks, 256, 0, stream>>>(rws, cls, vls, tmp, z_u, E);
      gemm64<<<(NU + 63) / 64, 256, 0, stream>>>(x_u, wcu + r * D_IN * O_OUT, tmp, NU);
      spmm_push<<<spmm_blocks, 256, 0, stream>>>(cls, rws, vls, tmp, z_v, E);
    }
    relu_f32<<<1024, 256, 0, stream>>>(out, n4_out);
  }
}

// Round 4
// 842.491 us; speedup vs baseline: 7.1067x; 2.0061x over previous
//
#include <hip/hip_runtime.h>
#include <hip/hip_bf16.h>

// Problem constants (shapes fixed by reference; N's derived from in_sizes)
#define R_SUP 5
#define D_IN 128
#define O_OUT 64
#define NBMAX 512          // max coarse buckets (N < 131072 guaranteed by 17-bit src field)
#define CHUNK 8192         // edges per workgroup in coarse_scatter

// fp32 -> bf16 round-to-nearest-even
__device__ __forceinline__ unsigned short f2bf(float f) {
  union { float f; unsigned int u; } c; c.f = f;
  unsigned int u = c.u;
  return (unsigned short)((u + 0x7FFFu + ((u >> 16) & 1u)) >> 16);
}
__device__ __forceinline__ float bf2f(unsigned short h) {
  return __uint_as_float(((unsigned int)h) << 16);
}

// ---------------------------------------------------------------------------
__global__ __launch_bounds__(256) void cumsum_w(
    const float* __restrict__ wu, const float* __restrict__ wv,
    float* __restrict__ wcu, float* __restrict__ wcv) {
  int i = blockIdx.x * 256 + threadIdx.x;
  if (i >= D_IN * O_OUT) return;
  float su = 0.f, sv = 0.f;
#pragma unroll
  for (int r = 0; r < R_SUP; ++r) {
    su += wu[r * D_IN * O_OUT + i];
    sv += wv[r * D_IN * O_OUT + i];
    wcu[r * D_IN * O_OUT + i] = su;
    wcv[r * D_IN * O_OUT + i] = sv;
  }
}

__global__ __launch_bounds__(256) void zero_f32(float* __restrict__ p, int n4) {
  int i = blockIdx.x * 256 + threadIdx.x;
  int stride = gridDim.x * 256;
  float4 z = make_float4(0.f, 0.f, 0.f, 0.f);
  for (; i < n4; i += stride) ((float4*)p)[i] = z;
}

__global__ __launch_bounds__(256) void zero_i32(int* __restrict__ p, int n) {
  int i = blockIdx.x * 256 + threadIdx.x;
  int stride = gridDim.x * 256;
  for (; i < n; i += stride) p[i] = 0;
}

// ---------------------------------------------------------------------------
// Batched GEMM: tmp5[r][n][o] = bf16( sum_d x[n][d]*wc[r][d][o] ), r=0..4
__global__ __launch_bounds__(256) void gemm5_bf16(
    const float* __restrict__ x, const float* __restrict__ wc,
    unsigned short* __restrict__ tmp5, size_t strideR, int N) {
  __shared__ float sXT[D_IN][68];
  __shared__ float sW[D_IN][O_OUT];
  const int tid = threadIdx.x;
  const int row0 = blockIdx.x * 64;

  for (int i = tid; i < 2048; i += 256) {
    int rl = i >> 5;
    int d4 = i & 31;
    int row = row0 + rl;
    float4 xv = make_float4(0.f, 0.f, 0.f, 0.f);
    if (row < N) xv = ((const float4*)x)[(size_t)row * 32 + d4];
    sXT[d4 * 4 + 0][rl] = xv.x;
    sXT[d4 * 4 + 1][rl] = xv.y;
    sXT[d4 * 4 + 2][rl] = xv.z;
    sXT[d4 * 4 + 3][rl] = xv.w;
  }

  const int col4 = (tid & 15) * 4;
  const int row4 = (tid >> 4) * 4;

  for (int r = 0; r < R_SUP; ++r) {
    __syncthreads();
    const float* wr = wc + r * D_IN * O_OUT;
    for (int i = tid; i < 2048; i += 256) {
      int d = i >> 4;
      int o4 = i & 15;
      ((float4*)&sW[d][0])[o4] = ((const float4*)wr)[i];
    }
    __syncthreads();

    float acc[4][4] = {};
#pragma unroll 8
    for (int d = 0; d < D_IN; ++d) {
      float4 xv = *(const float4*)&sXT[d][row4];
      float4 wv = *(const float4*)&sW[d][col4];
      acc[0][0] += xv.x * wv.x; acc[0][1] += xv.x * wv.y; acc[0][2] += xv.x * wv.z; acc[0][3] += xv.x * wv.w;
      acc[1][0] += xv.y * wv.x; acc[1][1] += xv.y * wv.y; acc[1][2] += xv.y * wv.z; acc[1][3] += xv.y * wv.w;
      acc[2][0] += xv.z * wv.x; acc[2][1] += xv.z * wv.y; acc[2][2] += xv.z * wv.z; acc[2][3] += xv.z * wv.w;
      acc[3][0] += xv.w * wv.x; acc[3][1] += xv.w * wv.y; acc[3][2] += xv.w * wv.z; acc[3][3] += xv.w * wv.w;
    }
#pragma unroll
    for (int i = 0; i < 4; ++i) {
      int row = row0 + row4 + i;
      if (row < N) {
        ushort4 h;
        h.x = f2bf(acc[i][0]);
        h.y = f2bf(acc[i][1]);
        h.z = f2bf(acc[i][2]);
        h.w = f2bf(acc[i][3]);
        *(ushort4*)&tmp5[r * strideR + (size_t)row * O_OUT + col4] = h;
      }
    }
  }
}

// ---------------------------------------------------------------------------
// Coarse bucket histogram for both directions (bucket = id >> 8), LDS-staged.
__global__ __launch_bounds__(256) void coarse_hist(
    const int* __restrict__ rows, const int* __restrict__ cols,
    int* __restrict__ cnt_u, int* __restrict__ cnt_v, int nE5,
    int nbu, int nbv) {
  __shared__ int hu[NBMAX], hv[NBMAX];
  const int tid = threadIdx.x;
  for (int t = tid; t < NBMAX; t += 256) { hu[t] = 0; hv[t] = 0; }
  __syncthreads();
  int i = blockIdx.x * 256 + tid;
  int stride = gridDim.x * 256;
  for (; i < nE5; i += stride) {
    atomicAdd(&hu[rows[i] >> 8], 1);
    atomicAdd(&hv[cols[i] >> 8], 1);
  }
  __syncthreads();
  for (int t = tid; t < nbu; t += 256) if (hu[t]) atomicAdd(&cnt_u[t], hu[t]);
  for (int t = tid; t < nbv; t += 256) if (hv[t]) atomicAdd(&cnt_v[t], hv[t]);
}

// Exclusive scan over coarse buckets. grid=2 (0->u, 1->v). Writes bucket
// bases cb[0..nb] and a working cursor copy gcur[0..nb).
__global__ __launch_bounds__(512) void coarse_scan(
    int* __restrict__ cnt_u, int* __restrict__ cnt_v,
    int* __restrict__ cb_u, int* __restrict__ cb_v,
    int* __restrict__ gcur_u, int* __restrict__ gcur_v, int nbu, int nbv) {
  int* cnt = blockIdx.x ? cnt_v : cnt_u;
  int* cb  = blockIdx.x ? cb_v  : cb_u;
  int* gc  = blockIdx.x ? gcur_v : gcur_u;
  int nb   = blockIdx.x ? nbv   : nbu;
  __shared__ int sc[NBMAX];
  const int t = threadIdx.x;
  sc[t] = (t < nb) ? cnt[t] : 0;
  __syncthreads();
  for (int off = 1; off < NBMAX; off <<= 1) {
    int add = (t >= off) ? sc[t - off] : 0;
    __syncthreads();
    sc[t] += add;
    __syncthreads();
  }
  int excl = t ? sc[t - 1] : 0;
  if (t < nb) { cb[t] = excl; gc[t] = excl; }
  if (t == 0) cb[nb] = sc[NBMAX - 1];
}

// Coarse scatter, both directions, LDS-staged run reservation.
// payload: x = dst_lo<<20 | r<<17 | src, y = val bits
__global__ __launch_bounds__(256) void coarse_scatter(
    const int* __restrict__ rows, const int* __restrict__ cols,
    const float* __restrict__ vals, int* __restrict__ gcur_u,
    int* __restrict__ gcur_v, int2* __restrict__ mid_u,
    int2* __restrict__ mid_v, int nE5, int E, int nbu, int nbv) {
  __shared__ int hu[NBMAX], hv[NBMAX], bu[NBMAX], bv[NBMAX];
  const int tid = threadIdx.x;
  const int base = blockIdx.x * CHUNK;
  const int end = min(base + CHUNK, nE5);
  for (int t = tid; t < NBMAX; t += 256) { hu[t] = 0; hv[t] = 0; }
  __syncthreads();
  for (int i = base + tid; i < end; i += 256) {
    atomicAdd(&hu[rows[i] >> 8], 1);
    atomicAdd(&hv[cols[i] >> 8], 1);
  }
  __syncthreads();
  for (int t = tid; t < nbu; t += 256) if (hu[t]) bu[t] = atomicAdd(&gcur_u[t], hu[t]);
  for (int t = tid; t < nbv; t += 256) if (hv[t]) bv[t] = atomicAdd(&gcur_v[t], hv[t]);
  __syncthreads();
  const int E2 = 2 * E, E3 = 3 * E, E4 = 4 * E;
  for (int i = base + tid; i < end; i += 256) {
    int rr = rows[i];
    int cc = cols[i];
    int vb = __float_as_int(vals[i]);
    int r = (i >= E) + (i >= E2) + (i >= E3) + (i >= E4);
    int rt = r << 17;
    int pu = atomicAdd(&bu[rr >> 8], 1);
    mid_u[pu] = make_int2(((rr & 255) << 20) | rt | cc, vb);
    int pv = atomicAdd(&bv[cc >> 8], 1);
    mid_v[pv] = make_int2(((cc & 255) << 20) | rt | rr, vb);
  }
}

// Fine scatter within one bucket (grid = nbuck). Builds per-dst rp and
// dst-sorted final entries (x = r<<17 | src). Output window is 64KB -> L2-hot.
__global__ __launch_bounds__(256) void fine_scatter(
    const int2* __restrict__ mid, const int* __restrict__ cb,
    int* __restrict__ rp, int2* __restrict__ fin, int nbuck, int Ndst) {
  __shared__ int h[256], sc[256], cur[256];
  const int tid = threadIdx.x;
  const int b = blockIdx.x;
  const int s = cb[b];
  const int e2 = cb[b + 1];
  h[tid] = 0;
  __syncthreads();
  for (int i = s + tid; i < e2; i += 256)
    atomicAdd(&h[(mid[i].x >> 20) & 255], 1);
  __syncthreads();
  sc[tid] = h[tid];
  __syncthreads();
  for (int off = 1; off < 256; off <<= 1) {
    int add = (tid >= off) ? sc[tid - off] : 0;
    __syncthreads();
    sc[tid] += add;
    __syncthreads();
  }
  int excl = tid ? sc[tid - 1] : 0;
  int d = b * 256 + tid;
  if (d <= Ndst) rp[d] = s + excl;
  if (b == nbuck - 1 && tid == 0 && Ndst >= nbuck * 256) rp[Ndst] = cb[nbuck];
  cur[tid] = s + excl;
  __syncthreads();
  for (int i = s + tid; i < e2; i += 256) {
    int2 pk = mid[i];
    int dl = (pk.x >> 20) & 255;
    int pos = atomicAdd(&cur[dl], 1);
    fin[pos] = make_int2(pk.x & 0xFFFFF, pk.y);
  }
}

// ---------------------------------------------------------------------------
// Pull SpMM fused over relations + ReLU. 16 lanes per destination row.
// entry: x = r<<17 | src (src < 2^17), y = val bits.
__global__ __launch_bounds__(256) void spmm_pull_bf16(
    const int* __restrict__ rp, const int2* __restrict__ ep,
    const unsigned short* __restrict__ tmp5, size_t strideR,
    float* __restrict__ z, int Ndst) {
  int g = (blockIdx.x * 256 + threadIdx.x) >> 4;
  int lane = threadIdx.x & 15;
  if (g >= Ndst) return;
  int s = rp[g];
  int e = rp[g + 1];
  float4 acc = make_float4(0.f, 0.f, 0.f, 0.f);
  for (int i = s; i < e; ++i) {
    int2 pk = ep[i];
    float v = __int_as_float(pk.y);
    int r = pk.x >> 17;
    int src = pk.x & 0x1FFFF;
    const ushort4* row =
        (const ushort4*)(tmp5 + (size_t)r * strideR + (size_t)src * O_OUT);
    ushort4 h = row[lane];
    acc.x += v * bf2f(h.x);
    acc.y += v * bf2f(h.y);
    acc.z += v * bf2f(h.z);
    acc.w += v * bf2f(h.w);
  }
  acc.x = acc.x > 0.f ? acc.x : 0.f;
  acc.y = acc.y > 0.f ? acc.y : 0.f;
  acc.z = acc.z > 0.f ? acc.z : 0.f;
  acc.w = acc.w > 0.f ? acc.w : 0.f;
  ((float4*)(z + (size_t)g * O_OUT))[lane] = acc;
}

// ---------------------------------------------------------------------------
// Fallback (push-atomic) kernels — only used if ws_size is tiny.
__global__ __launch_bounds__(256) void gemm64(
    const float* __restrict__ x, const float* __restrict__ w,
    float* __restrict__ out, int N) {
  __shared__ float sXT[D_IN][68];
  __shared__ float sW[D_IN][O_OUT];
  const int tid = threadIdx.x;
  const int row0 = blockIdx.x * 64;
  for (int i = tid; i < 2048; i += 256) {
    int d = i >> 4;
    int o4 = i & 15;
    ((float4*)&sW[d][0])[o4] = ((const float4*)w)[i];
  }
  for (int i = tid; i < 2048; i += 256) {
    int rl = i >> 5;
    int d4 = i & 31;
    int row = row0 + rl;
    float4 xv = make_float4(0.f, 0.f, 0.f, 0.f);
    if (row < N) xv = ((const float4*)x)[(size_t)row * 32 + d4];
    sXT[d4 * 4 + 0][rl] = xv.x;
    sXT[d4 * 4 + 1][rl] = xv.y;
    sXT[d4 * 4 + 2][rl] = xv.z;
    sXT[d4 * 4 + 3][rl] = xv.w;
  }
  __syncthreads();
  const int col4 = (tid & 15) * 4;
  const int row4 = (tid >> 4) * 4;
  float acc[4][4] = {};
#pragma unroll 8
  for (int d = 0; d < D_IN; ++d) {
    float4 xv = *(const float4*)&sXT[d][row4];
    float4 wv = *(const float4*)&sW[d][col4];
    acc[0][0] += xv.x * wv.x; acc[0][1] += xv.x * wv.y; acc[0][2] += xv.x * wv.z; acc[0][3] += xv.x * wv.w;
    acc[1][0] += xv.y * wv.x; acc[1][1] += xv.y * wv.y; acc[1][2] += xv.y * wv.z; acc[1][3] += xv.y * wv.w;
    acc[2][0] += xv.z * wv.x; acc[2][1] += xv.z * wv.y; acc[2][2] += xv.z * wv.z; acc[2][3] += xv.z * wv.w;
    acc[3][0] += xv.w * wv.x; acc[3][1] += xv.w * wv.y; acc[3][2] += xv.w * wv.z; acc[3][3] += xv.w * wv.w;
  }
#pragma unroll
  for (int i = 0; i < 4; ++i) {
    int row = row0 + row4 + i;
    if (row < N)
      *(float4*)&out[row * O_OUT + col4] =
          make_float4(acc[i][0], acc[i][1], acc[i][2], acc[i][3]);
  }
}

__global__ __launch_bounds__(256) void spmm_push(
    const int* __restrict__ dst, const int* __restrict__ src,
    const float* __restrict__ vals, const float* __restrict__ tmp,
    float* __restrict__ z, int E) {
  int t = blockIdx.x * 256 + threadIdx.x;
  int e = t >> 4;
  int lane = t & 15;
  if (e >= E) return;
  int d_ = dst[e];
  int s_ = src[e];
  float v = vals[e];
  float4 f = ((const float4*)tmp)[s_ * 16 + lane];
  float* zp = z + (size_t)d_ * O_OUT + lane * 4;
  atomicAdd(zp + 0, v * f.x);
  atomicAdd(zp + 1, v * f.y);
  atomicAdd(zp + 2, v * f.z);
  atomicAdd(zp + 3, v * f.w);
}

__global__ __launch_bounds__(256) void relu_f32(float* __restrict__ p, int n4) {
  int i = blockIdx.x * 256 + threadIdx.x;
  int stride = gridDim.x * 256;
  for (; i < n4; i += stride) {
    float4 v = ((float4*)p)[i];
    v.x = v.x > 0.f ? v.x : 0.f;
    v.y = v.y > 0.f ? v.y : 0.f;
    v.z = v.z > 0.f ? v.z : 0.f;
    v.w = v.w > 0.f ? v.w : 0.f;
    ((float4*)p)[i] = v;
  }
}

// ---------------------------------------------------------------------------
extern "C" void kernel_launch(void* const* d_in, const int* in_sizes, int n_in,
                              void* d_out, int out_size, void* d_ws, size_t ws_size,
                              hipStream_t stream) {
  const float* x_u      = (const float*)d_in[0];
  const float* x_v      = (const float*)d_in[1];
  const int*   sup_rows = (const int*)d_in[2];
  const int*   sup_cols = (const int*)d_in[3];
  const float* sup_vals = (const float*)d_in[4];
  const float* wu       = (const float*)d_in[5];
  const float* wv       = (const float*)d_in[6];

  const int NU = in_sizes[0] / D_IN;
  const int NV = in_sizes[1] / D_IN;
  const int E  = in_sizes[2] / R_SUP;
  const int Nmax = NU > NV ? NU : NV;
  const int nE5 = R_SUP * E;
  const int nbu = (NU + 255) / 256;
  const int nbv = (NV + 255) / 256;
  const int nbmax = nbu > nbv ? nbu : nbv;

  float* out = (float*)d_out;
  float* z_u = out;
  float* z_v = out + (size_t)NU * O_OUT;

  const int WDO = R_SUP * D_IN * O_OUT;  // 40960
  const size_t strideR = (size_t)Nmax * O_OUT;
  const size_t bpad = (size_t)nbmax + 16;

  // --- Radix path workspace layout ---
  // [mid_u int2 | mid_v int2 | fin int2 | tmp5 ushort | wcu | wcv | rp |
  //  cnt_u | cnt_v | cb_u | cb_v | gcur_u | gcur_v]
  const size_t needR = (size_t)nE5 * 24 + strideR * R_SUP * 2 +
                       (size_t)2 * WDO * 4 + ((size_t)Nmax + 16) * 4 +
                       6 * bpad * 4 + 256;

  if (ws_size >= needR && nbmax <= NBMAX && Nmax < (1 << 17)) {
    int2* mid_u = (int2*)d_ws;
    int2* mid_v = mid_u + nE5;
    int2* fin   = mid_v + nE5;
    unsigned short* tmp5 = (unsigned short*)(fin + nE5);
    float* wcu = (float*)(tmp5 + strideR * R_SUP);
    float* wcv = wcu + WDO;
    int* rp    = (int*)(wcv + WDO);
    int* cnt_u = rp + Nmax + 16;
    int* cnt_v = cnt_u + bpad;
    int* cb_u  = cnt_v + bpad;
    int* cb_v  = cb_u + bpad;
    int* gcur_u = cb_v + bpad;
    int* gcur_v = gcur_u + bpad;

    cumsum_w<<<(D_IN * O_OUT + 255) / 256, 256, 0, stream>>>(wu, wv, wcu, wcv);
    zero_i32<<<(2 * (int)bpad + 255) / 256, 256, 0, stream>>>(cnt_u, 2 * (int)bpad);
    coarse_hist<<<512, 256, 0, stream>>>(sup_rows, sup_cols, cnt_u, cnt_v,
                                         nE5, nbu, nbv);
    coarse_scan<<<2, 512, 0, stream>>>(cnt_u, cnt_v, cb_u, cb_v, gcur_u,
                                       gcur_v, nbu, nbv);
    coarse_scatter<<<(nE5 + CHUNK - 1) / CHUNK, 256, 0, stream>>>(
        sup_rows, sup_cols, sup_vals, gcur_u, gcur_v, mid_u, mid_v, nE5, E,
        nbu, nbv);

    // direction u: z_u = relu(sum_r S_r @ (x_v @ Wv_cum[r]))
    fine_scatter<<<nbu, 256, 0, stream>>>(mid_u, cb_u, rp, fin, nbu, NU);
    gemm5_bf16<<<(NV + 63) / 64, 256, 0, stream>>>(x_v, wcv, tmp5, strideR, NV);
    spmm_pull_bf16<<<(NU * 16 + 255) / 256, 256, 0, stream>>>(
        rp, fin, tmp5, strideR, z_u, NU);

    // direction v: z_v = relu(sum_r S_r^T @ (x_u @ Wu_cum[r]))
    fine_scatter<<<nbv, 256, 0, stream>>>(mid_v, cb_v, rp, fin, nbv, NV);
    gemm5_bf16<<<(NU + 63) / 64, 256, 0, stream>>>(x_u, wcu, tmp5, strideR, NU);
    spmm_pull_bf16<<<(NV * 16 + 255) / 256, 256, 0, stream>>>(
        rp, fin, tmp5, strideR, z_v, NV);
  } else {
    // ---- fallback: push-atomic path ----
    float* wcu = (float*)d_ws;
    float* wcv = wcu + WDO;
    float* tmp = wcv + WDO;
    const int n4_out = out_size / 4;
    cumsum_w<<<(D_IN * O_OUT + 255) / 256, 256, 0, stream>>>(wu, wv, wcu, wcv);
    zero_f32<<<1024, 256, 0, stream>>>(out, n4_out);
    const int spmm_blocks = (E * 16 + 255) / 256;
    for (int r = 0; r < R_SUP; ++r) {
      const int* rws = sup_rows + (size_t)r * E;
      const int* cls = sup_cols + (size_t)r * E;
      const float* vls = sup_vals + (size_t)r * E;
      gemm64<<<(NV + 63) / 64, 256, 0, stream>>>(x_v, wcv + r * D_IN * O_OUT, tmp, NV);
      spmm_push<<<spmm_blocks, 256, 0, stream>>>(rws, cls, vls, tmp, z_u, E);
      gemm64<<<(NU + 63) / 64, 256, 0, stream>>>(x_u, wcu + r * D_IN * O_OUT, tmp, NU);
      spmm_push<<<spmm_blocks, 256, 0, stream>>>(cls, rws, vls, tmp, z_v, E);
    }
    relu_f32<<<1024, 256, 0, stream>>>(out, n4_out);
  }
}

// Round 5
// 689.448 us; speedup vs baseline: 8.6842x; 1.2220x over previous
//
#include <hip/hip_runtime.h>
#include <hip/hip_bf16.h>

// Problem constants (shapes fixed by reference; N's derived from in_sizes)
#define R_SUP 5
#define D_IN 128
#define O_OUT 64
#define NBMAX 512          // max coarse buckets
#define CHUNK 8192         // edges per workgroup in coarse_scatter

typedef __attribute__((ext_vector_type(8))) short bf16x8;
typedef __attribute__((ext_vector_type(4))) float f32x4;

// fp32 -> bf16 round-to-nearest-even
__device__ __forceinline__ unsigned short f2bf(float f) {
  union { float f; unsigned int u; } c; c.f = f;
  unsigned int u = c.u;
  return (unsigned short)((u + 0x7FFFu + ((u >> 16) & 1u)) >> 16);
}
__device__ __forceinline__ float bf2f(unsigned short h) {
  return __uint_as_float(((unsigned int)h) << 16);
}

// ---------------------------------------------------------------------------
// cumsum over relation axis; emits fp32 cumsum (fallback path) AND transposed
// bf16 weights wtb[r][o][k] for the MFMA path. i indexes (d,o), o fastest.
__global__ __launch_bounds__(256) void cumsum_w(
    const float* __restrict__ wu, const float* __restrict__ wv,
    float* __restrict__ wcu, float* __restrict__ wcv,
    unsigned short* __restrict__ wtbu, unsigned short* __restrict__ wtbv) {
  int i = blockIdx.x * 256 + threadIdx.x;
  if (i >= D_IN * O_OUT) return;
  const int d = i >> 6;
  const int o = i & 63;
  float su = 0.f, sv = 0.f;
#pragma unroll
  for (int r = 0; r < R_SUP; ++r) {
    su += wu[r * D_IN * O_OUT + i];
    sv += wv[r * D_IN * O_OUT + i];
    wcu[r * D_IN * O_OUT + i] = su;
    wcv[r * D_IN * O_OUT + i] = sv;
    wtbu[((size_t)r * O_OUT + o) * D_IN + d] = f2bf(su);
    wtbv[((size_t)r * O_OUT + o) * D_IN + d] = f2bf(sv);
  }
}

// fp32 -> bf16 bulk convert (x matrices), float4 -> ushort4
__global__ __launch_bounds__(256) void cvt_bf16(
    const float* __restrict__ x, unsigned short* __restrict__ y, int n4) {
  int i = blockIdx.x * 256 + threadIdx.x;
  int stride = gridDim.x * 256;
  for (; i < n4; i += stride) {
    float4 v = ((const float4*)x)[i];
    ushort4 h;
    h.x = f2bf(v.x); h.y = f2bf(v.y); h.z = f2bf(v.z); h.w = f2bf(v.w);
    ((ushort4*)y)[i] = h;
  }
}

__global__ __launch_bounds__(256) void zero_f32(float* __restrict__ p, int n4) {
  int i = blockIdx.x * 256 + threadIdx.x;
  int stride = gridDim.x * 256;
  float4 z = make_float4(0.f, 0.f, 0.f, 0.f);
  for (; i < n4; i += stride) ((float4*)p)[i] = z;
}

__global__ __launch_bounds__(256) void zero_i32(int* __restrict__ p, int n) {
  int i = blockIdx.x * 256 + threadIdx.x;
  int stride = gridDim.x * 256;
  for (; i < n; i += stride) p[i] = 0;
}

// ---------------------------------------------------------------------------
// MFMA batched GEMM: tmp5[r][n][o] = bf16( sum_d xbf[n][d] * W[r][d][o] )
// xbf: [N][128] bf16.  wtb: [5][64][128] bf16 (W transposed, o-major).
// Block = 256 thr = 4 waves; block tile 64 rows; wave w -> cols [w*16,w*16+16).
// No LDS. A/B frags: lane m=l&15 row, k=(l>>4)*8 + j (m97-verified pattern).
__global__ __launch_bounds__(256) void gemm5_mfma(
    const unsigned short* __restrict__ xbf,
    const unsigned short* __restrict__ wtb,
    unsigned short* __restrict__ tmp5, size_t strideR, int N) {
  const int row0 = blockIdx.x * 64;
  const int wave = threadIdx.x >> 6;
  const int lane = threadIdx.x & 63;
  const int m = lane & 15;
  const int q = lane >> 4;
  const int o0 = wave * 16;

  bf16x8 a[4][4];  // [rowtile][k0] ; A[m][k] for rows row0+rt*16+m
#pragma unroll
  for (int rt = 0; rt < 4; ++rt) {
    int row = row0 + rt * 16 + m;
    if (row >= N) row = N - 1;  // clamp: loads harmless, stores guarded
    const unsigned short* px = xbf + (size_t)row * D_IN + q * 8;
#pragma unroll
    for (int k0 = 0; k0 < 4; ++k0)
      a[rt][k0] = *(const bf16x8*)(px + k0 * 32);
  }

  for (int r = 0; r < R_SUP; ++r) {
    bf16x8 b[4];
    const unsigned short* pw =
        wtb + ((size_t)r * O_OUT + o0 + m) * D_IN + q * 8;
#pragma unroll
    for (int k0 = 0; k0 < 4; ++k0)
      b[k0] = *(const bf16x8*)(pw + k0 * 32);
    unsigned short* pz = tmp5 + (size_t)r * strideR;
#pragma unroll
    for (int rt = 0; rt < 4; ++rt) {
      f32x4 acc = {0.f, 0.f, 0.f, 0.f};
#pragma unroll
      for (int k0 = 0; k0 < 4; ++k0)
        acc = __builtin_amdgcn_mfma_f32_16x16x32_bf16(a[rt][k0], b[k0], acc,
                                                      0, 0, 0);
      // C/D: col(n) = lane&15, row(m) = (lane>>4)*4 + reg  [m89/m91 verified]
#pragma unroll
      for (int reg = 0; reg < 4; ++reg) {
        int row = row0 + rt * 16 + q * 4 + reg;
        if (row < N) pz[(size_t)row * O_OUT + o0 + m] = f2bf(acc[reg]);
      }
    }
  }
}

// ---------------------------------------------------------------------------
// Coarse bucket histogram for both directions (bucket = id >> 8), LDS-staged.
__global__ __launch_bounds__(256) void coarse_hist(
    const int* __restrict__ rows, const int* __restrict__ cols,
    int* __restrict__ cnt_u, int* __restrict__ cnt_v, int nE5,
    int nbu, int nbv) {
  __shared__ int hu[NBMAX], hv[NBMAX];
  const int tid = threadIdx.x;
  for (int t = tid; t < NBMAX; t += 256) { hu[t] = 0; hv[t] = 0; }
  __syncthreads();
  int i = blockIdx.x * 256 + tid;
  int stride = gridDim.x * 256;
  for (; i < nE5; i += stride) {
    atomicAdd(&hu[rows[i] >> 8], 1);
    atomicAdd(&hv[cols[i] >> 8], 1);
  }
  __syncthreads();
  for (int t = tid; t < nbu; t += 256) if (hu[t]) atomicAdd(&cnt_u[t], hu[t]);
  for (int t = tid; t < nbv; t += 256) if (hv[t]) atomicAdd(&cnt_v[t], hv[t]);
}

// Exclusive scan over coarse buckets. grid=2 (0->u, 1->v).
__global__ __launch_bounds__(512) void coarse_scan(
    int* __restrict__ cnt_u, int* __restrict__ cnt_v,
    int* __restrict__ cb_u, int* __restrict__ cb_v,
    int* __restrict__ gcur_u, int* __restrict__ gcur_v, int nbu, int nbv) {
  int* cnt = blockIdx.x ? cnt_v : cnt_u;
  int* cb  = blockIdx.x ? cb_v  : cb_u;
  int* gc  = blockIdx.x ? gcur_v : gcur_u;
  int nb   = blockIdx.x ? nbv   : nbu;
  __shared__ int sc[NBMAX];
  const int t = threadIdx.x;
  sc[t] = (t < nb) ? cnt[t] : 0;
  __syncthreads();
  for (int off = 1; off < NBMAX; off <<= 1) {
    int add = (t >= off) ? sc[t - off] : 0;
    __syncthreads();
    sc[t] += add;
    __syncthreads();
  }
  int excl = t ? sc[t - 1] : 0;
  if (t < nb) { cb[t] = excl; gc[t] = excl; }
  if (t == 0) cb[nb] = sc[NBMAX - 1];
}

// Coarse scatter, both directions, LDS-staged run reservation.
// payload: x = dst_lo<<20 | r<<17 | src, y = val bits
__global__ __launch_bounds__(256) void coarse_scatter(
    const int* __restrict__ rows, const int* __restrict__ cols,
    const float* __restrict__ vals, int* __restrict__ gcur_u,
    int* __restrict__ gcur_v, int2* __restrict__ mid_u,
    int2* __restrict__ mid_v, int nE5, int E, int nbu, int nbv) {
  __shared__ int hu[NBMAX], hv[NBMAX], bu[NBMAX], bv[NBMAX];
  const int tid = threadIdx.x;
  const int base = blockIdx.x * CHUNK;
  const int end = min(base + CHUNK, nE5);
  for (int t = tid; t < NBMAX; t += 256) { hu[t] = 0; hv[t] = 0; }
  __syncthreads();
  for (int i = base + tid; i < end; i += 256) {
    atomicAdd(&hu[rows[i] >> 8], 1);
    atomicAdd(&hv[cols[i] >> 8], 1);
  }
  __syncthreads();
  for (int t = tid; t < nbu; t += 256) if (hu[t]) bu[t] = atomicAdd(&gcur_u[t], hu[t]);
  for (int t = tid; t < nbv; t += 256) if (hv[t]) bv[t] = atomicAdd(&gcur_v[t], hv[t]);
  __syncthreads();
  const int E2 = 2 * E, E3 = 3 * E, E4 = 4 * E;
  for (int i = base + tid; i < end; i += 256) {
    int rr = rows[i];
    int cc = cols[i];
    int vb = __float_as_int(vals[i]);
    int r = (i >= E) + (i >= E2) + (i >= E3) + (i >= E4);
    int rt = r << 17;
    int pu = atomicAdd(&bu[rr >> 8], 1);
    mid_u[pu] = make_int2(((rr & 255) << 20) | rt | cc, vb);
    int pv = atomicAdd(&bv[cc >> 8], 1);
    mid_v[pv] = make_int2(((cc & 255) << 20) | rt | rr, vb);
  }
}

// Fine scatter within one bucket (grid = nbuck). Builds per-dst rp and
// dst-sorted final entries (x = r<<17 | src). Output window is 64KB -> L2-hot.
__global__ __launch_bounds__(256) void fine_scatter(
    const int2* __restrict__ mid, const int* __restrict__ cb,
    int* __restrict__ rp, int2* __restrict__ fin, int nbuck, int Ndst) {
  __shared__ int h[256], sc[256], cur[256];
  const int tid = threadIdx.x;
  const int b = blockIdx.x;
  const int s = cb[b];
  const int e2 = cb[b + 1];
  h[tid] = 0;
  __syncthreads();
  for (int i = s + tid; i < e2; i += 256)
    atomicAdd(&h[(mid[i].x >> 20) & 255], 1);
  __syncthreads();
  sc[tid] = h[tid];
  __syncthreads();
  for (int off = 1; off < 256; off <<= 1) {
    int add = (tid >= off) ? sc[tid - off] : 0;
    __syncthreads();
    sc[tid] += add;
    __syncthreads();
  }
  int excl = tid ? sc[tid - 1] : 0;
  int d = b * 256 + tid;
  if (d <= Ndst) rp[d] = s + excl;
  if (b == nbuck - 1 && tid == 0 && Ndst >= nbuck * 256) rp[Ndst] = cb[nbuck];
  cur[tid] = s + excl;
  __syncthreads();
  for (int i = s + tid; i < e2; i += 256) {
    int2 pk = mid[i];
    int dl = (pk.x >> 20) & 255;
    int pos = atomicAdd(&cur[dl], 1);
    fin[pos] = make_int2(pk.x & 0xFFFFF, pk.y);
  }
}

// ---------------------------------------------------------------------------
// Pull SpMM fused over relations + ReLU. 16 lanes per destination row.
// entry: x = r<<17 | src (src < 2^17), y = val bits.
__global__ __launch_bounds__(256) void spmm_pull_bf16(
    const int* __restrict__ rp, const int2* __restrict__ ep,
    const unsigned short* __restrict__ tmp5, size_t strideR,
    float* __restrict__ z, int Ndst) {
  int g = (blockIdx.x * 256 + threadIdx.x) >> 4;
  int lane = threadIdx.x & 15;
  if (g >= Ndst) return;
  int s = rp[g];
  int e = rp[g + 1];
  float4 acc = make_float4(0.f, 0.f, 0.f, 0.f);
  for (int i = s; i < e; ++i) {
    int2 pk = ep[i];
    float v = __int_as_float(pk.y);
    int r = pk.x >> 17;
    int src = pk.x & 0x1FFFF;
    const ushort4* row =
        (const ushort4*)(tmp5 + (size_t)r * strideR + (size_t)src * O_OUT);
    ushort4 h = row[lane];
    acc.x += v * bf2f(h.x);
    acc.y += v * bf2f(h.y);
    acc.z += v * bf2f(h.z);
    acc.w += v * bf2f(h.w);
  }
  acc.x = acc.x > 0.f ? acc.x : 0.f;
  acc.y = acc.y > 0.f ? acc.y : 0.f;
  acc.z = acc.z > 0.f ? acc.z : 0.f;
  acc.w = acc.w > 0.f ? acc.w : 0.f;
  ((float4*)(z + (size_t)g * O_OUT))[lane] = acc;
}

// ---------------------------------------------------------------------------
// Fallback (push-atomic) kernels — only used if ws_size is tiny.
__global__ __launch_bounds__(256) void gemm64(
    const float* __restrict__ x, const float* __restrict__ w,
    float* __restrict__ out, int N) {
  __shared__ float sXT[D_IN][68];
  __shared__ float sW[D_IN][O_OUT];
  const int tid = threadIdx.x;
  const int row0 = blockIdx.x * 64;
  for (int i = tid; i < 2048; i += 256) {
    int d = i >> 4;
    int o4 = i & 15;
    ((float4*)&sW[d][0])[o4] = ((const float4*)w)[i];
  }
  for (int i = tid; i < 2048; i += 256) {
    int rl = i >> 5;
    int d4 = i & 31;
    int row = row0 + rl;
    float4 xv = make_float4(0.f, 0.f, 0.f, 0.f);
    if (row < N) xv = ((const float4*)x)[(size_t)row * 32 + d4];
    sXT[d4 * 4 + 0][rl] = xv.x;
    sXT[d4 * 4 + 1][rl] = xv.y;
    sXT[d4 * 4 + 2][rl] = xv.z;
    sXT[d4 * 4 + 3][rl] = xv.w;
  }
  __syncthreads();
  const int col4 = (tid & 15) * 4;
  const int row4 = (tid >> 4) * 4;
  float acc[4][4] = {};
#pragma unroll 8
  for (int d = 0; d < D_IN; ++d) {
    float4 xv = *(const float4*)&sXT[d][row4];
    float4 wv = *(const float4*)&sW[d][col4];
    acc[0][0] += xv.x * wv.x; acc[0][1] += xv.x * wv.y; acc[0][2] += xv.x * wv.z; acc[0][3] += xv.x * wv.w;
    acc[1][0] += xv.y * wv.x; acc[1][1] += xv.y * wv.y; acc[1][2] += xv.y * wv.z; acc[1][3] += xv.y * wv.w;
    acc[2][0] += xv.z * wv.x; acc[2][1] += xv.z * wv.y; acc[2][2] += xv.z * wv.z; acc[2][3] += xv.z * wv.w;
    acc[3][0] += xv.w * wv.x; acc[3][1] += xv.w * wv.y; acc[3][2] += xv.w * wv.z; acc[3][3] += xv.w * wv.w;
  }
#pragma unroll
  for (int i = 0; i < 4; ++i) {
    int row = row0 + row4 + i;
    if (row < N)
      *(float4*)&out[row * O_OUT + col4] =
          make_float4(acc[i][0], acc[i][1], acc[i][2], acc[i][3]);
  }
}

__global__ __launch_bounds__(256) void spmm_push(
    const int* __restrict__ dst, const int* __restrict__ src,
    const float* __restrict__ vals, const float* __restrict__ tmp,
    float* __restrict__ z, int E) {
  int t = blockIdx.x * 256 + threadIdx.x;
  int e = t >> 4;
  int lane = t & 15;
  if (e >= E) return;
  int d_ = dst[e];
  int s_ = src[e];
  float v = vals[e];
  float4 f = ((const float4*)tmp)[s_ * 16 + lane];
  float* zp = z + (size_t)d_ * O_OUT + lane * 4;
  atomicAdd(zp + 0, v * f.x);
  atomicAdd(zp + 1, v * f.y);
  atomicAdd(zp + 2, v * f.z);
  atomicAdd(zp + 3, v * f.w);
}

__global__ __launch_bounds__(256) void relu_f32(float* __restrict__ p, int n4) {
  int i = blockIdx.x * 256 + threadIdx.x;
  int stride = gridDim.x * 256;
  for (; i < n4; i += stride) {
    float4 v = ((float4*)p)[i];
    v.x = v.x > 0.f ? v.x : 0.f;
    v.y = v.y > 0.f ? v.y : 0.f;
    v.z = v.z > 0.f ? v.z : 0.f;
    v.w = v.w > 0.f ? v.w : 0.f;
    ((float4*)p)[i] = v;
  }
}

// ---------------------------------------------------------------------------
extern "C" void kernel_launch(void* const* d_in, const int* in_sizes, int n_in,
                              void* d_out, int out_size, void* d_ws, size_t ws_size,
                              hipStream_t stream) {
  const float* x_u      = (const float*)d_in[0];
  const float* x_v      = (const float*)d_in[1];
  const int*   sup_rows = (const int*)d_in[2];
  const int*   sup_cols = (const int*)d_in[3];
  const float* sup_vals = (const float*)d_in[4];
  const float* wu       = (const float*)d_in[5];
  const float* wv       = (const float*)d_in[6];

  const int NU = in_sizes[0] / D_IN;
  const int NV = in_sizes[1] / D_IN;
  const int E  = in_sizes[2] / R_SUP;
  const int Nmax = NU > NV ? NU : NV;
  const int nE5 = R_SUP * E;
  const int nbu = (NU + 255) / 256;
  const int nbv = (NV + 255) / 256;
  const int nbmax = nbu > nbv ? nbu : nbv;

  float* out = (float*)d_out;
  float* z_u = out;
  float* z_v = out + (size_t)NU * O_OUT;

  const int WDO = R_SUP * D_IN * O_OUT;  // 40960
  const size_t strideR = (size_t)Nmax * O_OUT;
  const size_t bpad = (size_t)nbmax + 16;

  // mid_u region doubles as the bf16-x buffer (dead after fine_scatter_u):
  const size_t midu_bytes_raw = (size_t)nE5 * 8;
  const size_t xbf_bytes = (size_t)Nmax * D_IN * 2;
  const size_t midu_bytes = ((midu_bytes_raw > xbf_bytes ? midu_bytes_raw
                                                         : xbf_bytes) + 255) & ~(size_t)255;

  // --- Radix path workspace layout ---
  // [mid_u/xbf | mid_v int2 | fin int2 | tmp5 ushort | wcu | wcv |
  //  wtbu ushort | wtbv ushort | rp | cnt_u | cnt_v | cb_u | cb_v | gcur_u | gcur_v]
  const size_t needR = midu_bytes + (size_t)nE5 * 16 + strideR * R_SUP * 2 +
                       (size_t)2 * WDO * 4 + (size_t)2 * WDO * 2 +
                       ((size_t)Nmax + 16) * 4 + 6 * bpad * 4 + 512;

  if (ws_size >= needR && nbmax <= NBMAX && Nmax < (1 << 17)) {
    char* base = (char*)d_ws;
    int2* mid_u = (int2*)base;
    unsigned short* xbf = (unsigned short*)base;  // alias (after fine_u)
    int2* mid_v = (int2*)(base + midu_bytes);
    int2* fin   = mid_v + nE5;
    unsigned short* tmp5 = (unsigned short*)(fin + nE5);
    float* wcu = (float*)(tmp5 + strideR * R_SUP);
    float* wcv = wcu + WDO;
    unsigned short* wtbu = (unsigned short*)(wcv + WDO);
    unsigned short* wtbv = wtbu + WDO;
    int* rp    = (int*)(wtbv + WDO);
    int* cnt_u = rp + Nmax + 16;
    int* cnt_v = cnt_u + bpad;
    int* cb_u  = cnt_v + bpad;
    int* cb_v  = cb_u + bpad;
    int* gcur_u = cb_v + bpad;
    int* gcur_v = gcur_u + bpad;

    cumsum_w<<<(D_IN * O_OUT + 255) / 256, 256, 0, stream>>>(
        wu, wv, wcu, wcv, wtbu, wtbv);
    zero_i32<<<(2 * (int)bpad + 255) / 256, 256, 0, stream>>>(cnt_u, 2 * (int)bpad);
    coarse_hist<<<512, 256, 0, stream>>>(sup_rows, sup_cols, cnt_u, cnt_v,
                                         nE5, nbu, nbv);
    coarse_scan<<<2, 512, 0, stream>>>(cnt_u, cnt_v, cb_u, cb_v, gcur_u,
                                       gcur_v, nbu, nbv);
    coarse_scatter<<<(nE5 + CHUNK - 1) / CHUNK, 256, 0, stream>>>(
        sup_rows, sup_cols, sup_vals, gcur_u, gcur_v, mid_u, mid_v, nE5, E,
        nbu, nbv);

    // ---- direction u: z_u = relu(sum_r S_r @ (x_v @ Wv_cum[r])) ----
    fine_scatter<<<nbu, 256, 0, stream>>>(mid_u, cb_u, rp, fin, nbu, NU);
    // mid_u now dead -> reuse as bf16 x_v
    cvt_bf16<<<1024, 256, 0, stream>>>(x_v, xbf, NV * D_IN / 4);
    gemm5_mfma<<<(NV + 63) / 64, 256, 0, stream>>>(xbf, wtbv, tmp5, strideR, NV);
    spmm_pull_bf16<<<(NU * 16 + 255) / 256, 256, 0, stream>>>(
        rp, fin, tmp5, strideR, z_u, NU);

    // ---- direction v: z_v = relu(sum_r S_r^T @ (x_u @ Wu_cum[r])) ----
    fine_scatter<<<nbv, 256, 0, stream>>>(mid_v, cb_v, rp, fin, nbv, NV);
    cvt_bf16<<<1024, 256, 0, stream>>>(x_u, xbf, NU * D_IN / 4);
    gemm5_mfma<<<(NU + 63) / 64, 256, 0, stream>>>(xbf, wtbu, tmp5, strideR, NU);
    spmm_pull_bf16<<<(NV * 16 + 255) / 256, 256, 0, stream>>>(
        rp, fin, tmp5, strideR, z_v, NV);
  } else {
    // ---- fallback: push-atomic path ----
    float* wcu = (float*)d_ws;
    float* wcv = wcu + WDO;
    unsigned short* wtbu = (unsigned short*)(wcv + WDO);
    unsigned short* wtbv = wtbu + WDO;
    float* tmp = (float*)(wtbv + WDO);
    const int n4_out = out_size / 4;
    cumsum_w<<<(D_IN * O_OUT + 255) / 256, 256, 0, stream>>>(
        wu, wv, wcu, wcv, wtbu, wtbv);
    zero_f32<<<1024, 256, 0, stream>>>(out, n4_out);
    const int spmm_blocks = (E * 16 + 255) / 256;
    for (int r = 0; r < R_SUP; ++r) {
      const int* rws = sup_rows + (size_t)r * E;
      const int* cls = sup_cols + (size_t)r * E;
      const float* vls = sup_vals + (size_t)r * E;
      gemm64<<<(NV + 63) / 64, 256, 0, stream>>>(x_v, wcv + r * D_IN * O_OUT, tmp, NV);
      spmm_push<<<spmm_blocks, 256, 0, stream>>>(rws, cls, vls, tmp, z_u, E);
      gemm64<<<(NU + 63) / 64, 256, 0, stream>>>(x_u, wcu + r * D_IN * O_OUT, tmp, NU);
      spmm_push<<<spmm_blocks, 256, 0, stream>>>(cls, rws, vls, tmp, z_v, E);
    }
    relu_f32<<<1024, 256, 0, stream>>>(out, n4_out);
  }
}

// Round 6
// 625.159 us; speedup vs baseline: 9.5773x; 1.1028x over previous
//
#include <hip/hip_runtime.h>
#include <hip/hip_bf16.h>

// Problem constants (shapes fixed by reference; N's derived from in_sizes)
#define R_SUP 5
#define D_IN 128
#define O_OUT 64
#define NBMAX 512          // max coarse buckets
#define CHUNK 8192         // edges per workgroup in coarse_scatter

typedef __attribute__((ext_vector_type(8))) short bf16x8;
typedef __attribute__((ext_vector_type(4))) float f32x4;

// fp32 -> bf16 round-to-nearest-even
__device__ __forceinline__ unsigned short f2bf(float f) {
  union { float f; unsigned int u; } c; c.f = f;
  unsigned int u = c.u;
  return (unsigned short)((u + 0x7FFFu + ((u >> 16) & 1u)) >> 16);
}
__device__ __forceinline__ float bf2f(unsigned short h) {
  return __uint_as_float(((unsigned int)h) << 16);
}

// ---------------------------------------------------------------------------
// cumsum over relation axis; emits fp32 cumsum (fallback path) AND transposed
// bf16 weights wtb[r][o][k] for the MFMA path. i indexes (d,o), o fastest.
__global__ __launch_bounds__(256) void cumsum_w(
    const float* __restrict__ wu, const float* __restrict__ wv,
    float* __restrict__ wcu, float* __restrict__ wcv,
    unsigned short* __restrict__ wtbu, unsigned short* __restrict__ wtbv) {
  int i = blockIdx.x * 256 + threadIdx.x;
  if (i >= D_IN * O_OUT) return;
  const int d = i >> 6;
  const int o = i & 63;
  float su = 0.f, sv = 0.f;
#pragma unroll
  for (int r = 0; r < R_SUP; ++r) {
    su += wu[r * D_IN * O_OUT + i];
    sv += wv[r * D_IN * O_OUT + i];
    wcu[r * D_IN * O_OUT + i] = su;
    wcv[r * D_IN * O_OUT + i] = sv;
    wtbu[((size_t)r * O_OUT + o) * D_IN + d] = f2bf(su);
    wtbv[((size_t)r * O_OUT + o) * D_IN + d] = f2bf(sv);
  }
}

// fp32 -> bf16 bulk convert (x matrices), float4 -> ushort4
__global__ __launch_bounds__(256) void cvt_bf16(
    const float* __restrict__ x, unsigned short* __restrict__ y, int n4) {
  int i = blockIdx.x * 256 + threadIdx.x;
  int stride = gridDim.x * 256;
  for (; i < n4; i += stride) {
    float4 v = ((const float4*)x)[i];
    ushort4 h;
    h.x = f2bf(v.x); h.y = f2bf(v.y); h.z = f2bf(v.z); h.w = f2bf(v.w);
    ((ushort4*)y)[i] = h;
  }
}

__global__ __launch_bounds__(256) void zero_f32(float* __restrict__ p, int n4) {
  int i = blockIdx.x * 256 + threadIdx.x;
  int stride = gridDim.x * 256;
  float4 z = make_float4(0.f, 0.f, 0.f, 0.f);
  for (; i < n4; i += stride) ((float4*)p)[i] = z;
}

__global__ __launch_bounds__(256) void zero_i32(int* __restrict__ p, int n) {
  int i = blockIdx.x * 256 + threadIdx.x;
  int stride = gridDim.x * 256;
  for (; i < n; i += stride) p[i] = 0;
}

// ---------------------------------------------------------------------------
// MFMA batched GEMM: tmp5[r][n][o] = bf16( sum_d xbf[n][d] * W[r][d][o] )
// xbf: [N][128] bf16.  wtb: [5][64][128] bf16 (W transposed, o-major).
__global__ __launch_bounds__(256) void gemm5_mfma(
    const unsigned short* __restrict__ xbf,
    const unsigned short* __restrict__ wtb,
    unsigned short* __restrict__ tmp5, size_t strideR, int N) {
  const int row0 = blockIdx.x * 64;
  const int wave = threadIdx.x >> 6;
  const int lane = threadIdx.x & 63;
  const int m = lane & 15;
  const int q = lane >> 4;
  const int o0 = wave * 16;

  bf16x8 a[4][4];
#pragma unroll
  for (int rt = 0; rt < 4; ++rt) {
    int row = row0 + rt * 16 + m;
    if (row >= N) row = N - 1;  // clamp: loads harmless, stores guarded
    const unsigned short* px = xbf + (size_t)row * D_IN + q * 8;
#pragma unroll
    for (int k0 = 0; k0 < 4; ++k0)
      a[rt][k0] = *(const bf16x8*)(px + k0 * 32);
  }

  for (int r = 0; r < R_SUP; ++r) {
    bf16x8 b[4];
    const unsigned short* pw =
        wtb + ((size_t)r * O_OUT + o0 + m) * D_IN + q * 8;
#pragma unroll
    for (int k0 = 0; k0 < 4; ++k0)
      b[k0] = *(const bf16x8*)(pw + k0 * 32);
    unsigned short* pz = tmp5 + (size_t)r * strideR;
#pragma unroll
    for (int rt = 0; rt < 4; ++rt) {
      f32x4 acc = {0.f, 0.f, 0.f, 0.f};
#pragma unroll
      for (int k0 = 0; k0 < 4; ++k0)
        acc = __builtin_amdgcn_mfma_f32_16x16x32_bf16(a[rt][k0], b[k0], acc,
                                                      0, 0, 0);
#pragma unroll
      for (int reg = 0; reg < 4; ++reg) {
        int row = row0 + rt * 16 + q * 4 + reg;
        if (row < N) pz[(size_t)row * O_OUT + o0 + m] = f2bf(acc[reg]);
      }
    }
  }
}

// ---------------------------------------------------------------------------
// Coarse bucket histogram, both directions, int4-vectorized edge loads.
__global__ __launch_bounds__(256) void coarse_hist(
    const int* __restrict__ rows, const int* __restrict__ cols,
    int* __restrict__ cnt_u, int* __restrict__ cnt_v, int nE5,
    int nbu, int nbv) {
  __shared__ int hu[NBMAX], hv[NBMAX];
  const int tid = threadIdx.x;
  for (int t = tid; t < NBMAX; t += 256) { hu[t] = 0; hv[t] = 0; }
  __syncthreads();
  const int n4 = nE5 >> 2;
  int i = blockIdx.x * 256 + tid;
  int stride = gridDim.x * 256;
  for (; i < n4; i += stride) {
    int4 rr = ((const int4*)rows)[i];
    int4 cc = ((const int4*)cols)[i];
    atomicAdd(&hu[rr.x >> 8], 1); atomicAdd(&hu[rr.y >> 8], 1);
    atomicAdd(&hu[rr.z >> 8], 1); atomicAdd(&hu[rr.w >> 8], 1);
    atomicAdd(&hv[cc.x >> 8], 1); atomicAdd(&hv[cc.y >> 8], 1);
    atomicAdd(&hv[cc.z >> 8], 1); atomicAdd(&hv[cc.w >> 8], 1);
  }
  // tail
  for (i = (n4 << 2) + blockIdx.x * 256 + tid; i < nE5; i += stride) {
    atomicAdd(&hu[rows[i] >> 8], 1);
    atomicAdd(&hv[cols[i] >> 8], 1);
  }
  __syncthreads();
  for (int t = tid; t < nbu; t += 256) if (hu[t]) atomicAdd(&cnt_u[t], hu[t]);
  for (int t = tid; t < nbv; t += 256) if (hv[t]) atomicAdd(&cnt_v[t], hv[t]);
}

// Exclusive scan over coarse buckets. grid=2 (0->u, 1->v).
__global__ __launch_bounds__(512) void coarse_scan(
    int* __restrict__ cnt_u, int* __restrict__ cnt_v,
    int* __restrict__ cb_u, int* __restrict__ cb_v,
    int* __restrict__ gcur_u, int* __restrict__ gcur_v, int nbu, int nbv) {
  int* cnt = blockIdx.x ? cnt_v : cnt_u;
  int* cb  = blockIdx.x ? cb_v  : cb_u;
  int* gc  = blockIdx.x ? gcur_v : gcur_u;
  int nb   = blockIdx.x ? nbv   : nbu;
  __shared__ int sc[NBMAX];
  const int t = threadIdx.x;
  sc[t] = (t < nb) ? cnt[t] : 0;
  __syncthreads();
  for (int off = 1; off < NBMAX; off <<= 1) {
    int add = (t >= off) ? sc[t - off] : 0;
    __syncthreads();
    sc[t] += add;
    __syncthreads();
  }
  int excl = t ? sc[t - 1] : 0;
  if (t < nb) { cb[t] = excl; gc[t] = excl; }
  if (t == 0) cb[nb] = sc[NBMAX - 1];
}

// ---------------------------------------------------------------------------
// Coarse scatter, LDS-staged + bucket-sorted + coalesced run flush.
// Per chunk: hist -> scan -> place into LDS sorted by bucket -> reserve
// global runs -> flush runs with lane-consecutive stores (full-line bursts).
// Both directions in one block (edge chunk is L2-hot for phase 2).
// payload: x = dst_lo<<20 | r<<17 | src, y = val bits
__global__ __launch_bounds__(512) void coarse_scatter(
    const int* __restrict__ rows, const int* __restrict__ cols,
    const float* __restrict__ vals, int* __restrict__ gcur_u,
    int* __restrict__ gcur_v, int2* __restrict__ mid_u,
    int2* __restrict__ mid_v, int nE5, int E, int nbu, int nbv) {
  __shared__ int2 buf[CHUNK];            // 64 KB
  __shared__ int h[NBMAX], sc[NBMAX], gb[NBMAX], cur[NBMAX];  // 8 KB
  const int tid = threadIdx.x;
  const int base = blockIdx.x * CHUNK;
  const int end = min(base + CHUNK, nE5);
  const int E2 = 2 * E, E3 = 3 * E, E4 = 4 * E;

#pragma unroll
  for (int dir = 0; dir < 2; ++dir) {
    const int* ids   = dir ? cols : rows;
    const int* other = dir ? rows : cols;
    int* gcur = dir ? gcur_v : gcur_u;
    int2* mid = dir ? mid_v : mid_u;
    const int nb = dir ? nbv : nbu;

    if (dir) __syncthreads();  // protect LDS reuse across directions
    h[tid] = 0;                // tid < 512 == NBMAX
    __syncthreads();
    // 1. histogram of this chunk
    for (int i = base + tid; i < end; i += 512)
      atomicAdd(&h[ids[i] >> 8], 1);
    __syncthreads();
    // 2. inclusive scan (Hillis-Steele, 512 threads == NBMAX elems)
    sc[tid] = h[tid];
    __syncthreads();
    for (int off = 1; off < NBMAX; off <<= 1) {
      int add = (tid >= off) ? sc[tid - off] : 0;
      __syncthreads();
      sc[tid] += add;
      __syncthreads();
    }
    // 3. reserve global runs; init local cursors to exclusive scan
    int excl = tid ? sc[tid - 1] : 0;
    cur[tid] = excl;
    if (tid < nb && h[tid]) gb[tid] = atomicAdd(&gcur[tid], h[tid]);
    __syncthreads();
    // 4. place payloads into LDS, bucket-sorted
    for (int i = base + tid; i < end; i += 512) {
      int id = ids[i];
      int src = other[i];
      int vb = __float_as_int(vals[i]);
      int r = (i >= E) + (i >= E2) + (i >= E3) + (i >= E4);
      int pos = atomicAdd(&cur[id >> 8], 1);
      buf[pos] = make_int2(((id & 255) << 20) | (r << 17) | src, vb);
    }
    __syncthreads();
    // 5. flush runs: wave w handles buckets w, w+8, ...; lanes consecutive
    const int wv = tid >> 6;
    const int lane = tid & 63;
    for (int b = wv; b < nb; b += 8) {
      int s = b ? sc[b - 1] : 0;
      int e = sc[b];
      if (s == e) continue;
      int2* dst = mid + gb[b];
      for (int j = s + lane; j < e; j += 64) dst[j - s] = buf[j];
    }
  }
}

// Fine scatter within one bucket (grid = nbuck). Builds per-dst rp and
// dst-sorted final entries (x = r<<17 | src). Output window is 64KB -> L2-hot.
__global__ __launch_bounds__(256) void fine_scatter(
    const int2* __restrict__ mid, const int* __restrict__ cb,
    int* __restrict__ rp, int2* __restrict__ fin, int nbuck, int Ndst) {
  __shared__ int h[256], sc[256], cur[256];
  const int tid = threadIdx.x;
  const int b = blockIdx.x;
  const int s = cb[b];
  const int e2 = cb[b + 1];
  h[tid] = 0;
  __syncthreads();
  for (int i = s + tid; i < e2; i += 256)
    atomicAdd(&h[(mid[i].x >> 20) & 255], 1);
  __syncthreads();
  sc[tid] = h[tid];
  __syncthreads();
  for (int off = 1; off < 256; off <<= 1) {
    int add = (tid >= off) ? sc[tid - off] : 0;
    __syncthreads();
    sc[tid] += add;
    __syncthreads();
  }
  int excl = tid ? sc[tid - 1] : 0;
  int d = b * 256 + tid;
  if (d <= Ndst) rp[d] = s + excl;
  if (b == nbuck - 1 && tid == 0 && Ndst >= nbuck * 256) rp[Ndst] = cb[nbuck];
  cur[tid] = s + excl;
  __syncthreads();
  for (int i = s + tid; i < e2; i += 256) {
    int2 pk = mid[i];
    int dl = (pk.x >> 20) & 255;
    int pos = atomicAdd(&cur[dl], 1);
    fin[pos] = make_int2(pk.x & 0xFFFFF, pk.y);
  }
}

// ---------------------------------------------------------------------------
// Pull SpMM fused over relations + ReLU. 16 lanes per destination row.
// entry: x = r<<17 | src (src < 2^17), y = val bits.
__global__ __launch_bounds__(256) void spmm_pull_bf16(
    const int* __restrict__ rp, const int2* __restrict__ ep,
    const unsigned short* __restrict__ tmp5, size_t strideR,
    float* __restrict__ z, int Ndst) {
  int g = (blockIdx.x * 256 + threadIdx.x) >> 4;
  int lane = threadIdx.x & 15;
  if (g >= Ndst) return;
  int s = rp[g];
  int e = rp[g + 1];
  float4 acc = make_float4(0.f, 0.f, 0.f, 0.f);
  for (int i = s; i < e; ++i) {
    int2 pk = ep[i];
    float v = __int_as_float(pk.y);
    int r = pk.x >> 17;
    int src = pk.x & 0x1FFFF;
    const ushort4* row =
        (const ushort4*)(tmp5 + (size_t)r * strideR + (size_t)src * O_OUT);
    ushort4 h = row[lane];
    acc.x += v * bf2f(h.x);
    acc.y += v * bf2f(h.y);
    acc.z += v * bf2f(h.z);
    acc.w += v * bf2f(h.w);
  }
  acc.x = acc.x > 0.f ? acc.x : 0.f;
  acc.y = acc.y > 0.f ? acc.y : 0.f;
  acc.z = acc.z > 0.f ? acc.z : 0.f;
  acc.w = acc.w > 0.f ? acc.w : 0.f;
  ((float4*)(z + (size_t)g * O_OUT))[lane] = acc;
}

// ---------------------------------------------------------------------------
// Fallback (push-atomic) kernels — only used if ws_size is tiny.
__global__ __launch_bounds__(256) void gemm64(
    const float* __restrict__ x, const float* __restrict__ w,
    float* __restrict__ out, int N) {
  __shared__ float sXT[D_IN][68];
  __shared__ float sW[D_IN][O_OUT];
  const int tid = threadIdx.x;
  const int row0 = blockIdx.x * 64;
  for (int i = tid; i < 2048; i += 256) {
    int d = i >> 4;
    int o4 = i & 15;
    ((float4*)&sW[d][0])[o4] = ((const float4*)w)[i];
  }
  for (int i = tid; i < 2048; i += 256) {
    int rl = i >> 5;
    int d4 = i & 31;
    int row = row0 + rl;
    float4 xv = make_float4(0.f, 0.f, 0.f, 0.f);
    if (row < N) xv = ((const float4*)x)[(size_t)row * 32 + d4];
    sXT[d4 * 4 + 0][rl] = xv.x;
    sXT[d4 * 4 + 1][rl] = xv.y;
    sXT[d4 * 4 + 2][rl] = xv.z;
    sXT[d4 * 4 + 3][rl] = xv.w;
  }
  __syncthreads();
  const int col4 = (tid & 15) * 4;
  const int row4 = (tid >> 4) * 4;
  float acc[4][4] = {};
#pragma unroll 8
  for (int d = 0; d < D_IN; ++d) {
    float4 xv = *(const float4*)&sXT[d][row4];
    float4 wv = *(const float4*)&sW[d][col4];
    acc[0][0] += xv.x * wv.x; acc[0][1] += xv.x * wv.y; acc[0][2] += xv.x * wv.z; acc[0][3] += xv.x * wv.w;
    acc[1][0] += xv.y * wv.x; acc[1][1] += xv.y * wv.y; acc[1][2] += xv.y * wv.z; acc[1][3] += xv.y * wv.w;
    acc[2][0] += xv.z * wv.x; acc[2][1] += xv.z * wv.y; acc[2][2] += xv.z * wv.z; acc[2][3] += xv.z * wv.w;
    acc[3][0] += xv.w * wv.x; acc[3][1] += xv.w * wv.y; acc[3][2] += xv.w * wv.z; acc[3][3] += xv.w * wv.w;
  }
#pragma unroll
  for (int i = 0; i < 4; ++i) {
    int row = row0 + row4 + i;
    if (row < N)
      *(float4*)&out[row * O_OUT + col4] =
          make_float4(acc[i][0], acc[i][1], acc[i][2], acc[i][3]);
  }
}

__global__ __launch_bounds__(256) void spmm_push(
    const int* __restrict__ dst, const int* __restrict__ src,
    const float* __restrict__ vals, const float* __restrict__ tmp,
    float* __restrict__ z, int E) {
  int t = blockIdx.x * 256 + threadIdx.x;
  int e = t >> 4;
  int lane = t & 15;
  if (e >= E) return;
  int d_ = dst[e];
  int s_ = src[e];
  float v = vals[e];
  float4 f = ((const float4*)tmp)[s_ * 16 + lane];
  float* zp = z + (size_t)d_ * O_OUT + lane * 4;
  atomicAdd(zp + 0, v * f.x);
  atomicAdd(zp + 1, v * f.y);
  atomicAdd(zp + 2, v * f.z);
  atomicAdd(zp + 3, v * f.w);
}

__global__ __launch_bounds__(256) void relu_f32(float* __restrict__ p, int n4) {
  int i = blockIdx.x * 256 + threadIdx.x;
  int stride = gridDim.x * 256;
  for (; i < n4; i += stride) {
    float4 v = ((float4*)p)[i];
    v.x = v.x > 0.f ? v.x : 0.f;
    v.y = v.y > 0.f ? v.y : 0.f;
    v.z = v.z > 0.f ? v.z : 0.f;
    v.w = v.w > 0.f ? v.w : 0.f;
    ((float4*)p)[i] = v;
  }
}

// ---------------------------------------------------------------------------
extern "C" void kernel_launch(void* const* d_in, const int* in_sizes, int n_in,
                              void* d_out, int out_size, void* d_ws, size_t ws_size,
                              hipStream_t stream) {
  const float* x_u      = (const float*)d_in[0];
  const float* x_v      = (const float*)d_in[1];
  const int*   sup_rows = (const int*)d_in[2];
  const int*   sup_cols = (const int*)d_in[3];
  const float* sup_vals = (const float*)d_in[4];
  const float* wu       = (const float*)d_in[5];
  const float* wv       = (const float*)d_in[6];

  const int NU = in_sizes[0] / D_IN;
  const int NV = in_sizes[1] / D_IN;
  const int E  = in_sizes[2] / R_SUP;
  const int Nmax = NU > NV ? NU : NV;
  const int nE5 = R_SUP * E;
  const int nbu = (NU + 255) / 256;
  const int nbv = (NV + 255) / 256;
  const int nbmax = nbu > nbv ? nbu : nbv;

  float* out = (float*)d_out;
  float* z_u = out;
  float* z_v = out + (size_t)NU * O_OUT;

  const int WDO = R_SUP * D_IN * O_OUT;  // 40960
  const size_t strideR = (size_t)Nmax * O_OUT;
  const size_t bpad = (size_t)nbmax + 16;

  // mid_u region doubles as the bf16-x buffer (dead after fine_scatter_u):
  const size_t midu_bytes_raw = (size_t)nE5 * 8;
  const size_t xbf_bytes = (size_t)Nmax * D_IN * 2;
  const size_t midu_bytes = ((midu_bytes_raw > xbf_bytes ? midu_bytes_raw
                                                         : xbf_bytes) + 255) & ~(size_t)255;

  // --- Radix path workspace layout ---
  const size_t needR = midu_bytes + (size_t)nE5 * 16 + strideR * R_SUP * 2 +
                       (size_t)2 * WDO * 4 + (size_t)2 * WDO * 2 +
                       ((size_t)Nmax + 16) * 4 + 6 * bpad * 4 + 512;

  if (ws_size >= needR && nbmax <= NBMAX && Nmax < (1 << 17)) {
    char* base = (char*)d_ws;
    int2* mid_u = (int2*)base;
    unsigned short* xbf = (unsigned short*)base;  // alias (after fine_u)
    int2* mid_v = (int2*)(base + midu_bytes);
    int2* fin   = mid_v + nE5;
    unsigned short* tmp5 = (unsigned short*)(fin + nE5);
    float* wcu = (float*)(tmp5 + strideR * R_SUP);
    float* wcv = wcu + WDO;
    unsigned short* wtbu = (unsigned short*)(wcv + WDO);
    unsigned short* wtbv = wtbu + WDO;
    int* rp    = (int*)(wtbv + WDO);
    int* cnt_u = rp + Nmax + 16;
    int* cnt_v = cnt_u + bpad;
    int* cb_u  = cnt_v + bpad;
    int* cb_v  = cb_u + bpad;
    int* gcur_u = cb_v + bpad;
    int* gcur_v = gcur_u + bpad;

    cumsum_w<<<(D_IN * O_OUT + 255) / 256, 256, 0, stream>>>(
        wu, wv, wcu, wcv, wtbu, wtbv);
    zero_i32<<<(2 * (int)bpad + 255) / 256, 256, 0, stream>>>(cnt_u, 2 * (int)bpad);
    coarse_hist<<<512, 256, 0, stream>>>(sup_rows, sup_cols, cnt_u, cnt_v,
                                         nE5, nbu, nbv);
    coarse_scan<<<2, 512, 0, stream>>>(cnt_u, cnt_v, cb_u, cb_v, gcur_u,
                                       gcur_v, nbu, nbv);
    coarse_scatter<<<(nE5 + CHUNK - 1) / CHUNK, 512, 0, stream>>>(
        sup_rows, sup_cols, sup_vals, gcur_u, gcur_v, mid_u, mid_v, nE5, E,
        nbu, nbv);

    // ---- direction u: z_u = relu(sum_r S_r @ (x_v @ Wv_cum[r])) ----
    fine_scatter<<<nbu, 256, 0, stream>>>(mid_u, cb_u, rp, fin, nbu, NU);
    // mid_u now dead -> reuse as bf16 x_v
    cvt_bf16<<<1024, 256, 0, stream>>>(x_v, xbf, NV * D_IN / 4);
    gemm5_mfma<<<(NV + 63) / 64, 256, 0, stream>>>(xbf, wtbv, tmp5, strideR, NV);
    spmm_pull_bf16<<<(NU * 16 + 255) / 256, 256, 0, stream>>>(
        rp, fin, tmp5, strideR, z_u, NU);

    // ---- direction v: z_v = relu(sum_r S_r^T @ (x_u @ Wu_cum[r])) ----
    fine_scatter<<<nbv, 256, 0, stream>>>(mid_v, cb_v, rp, fin, nbv, NV);
    cvt_bf16<<<1024, 256, 0, stream>>>(x_u, xbf, NU * D_IN / 4);
    gemm5_mfma<<<(NU + 63) / 64, 256, 0, stream>>>(xbf, wtbu, tmp5, strideR, NU);
    spmm_pull_bf16<<<(NV * 16 + 255) / 256, 256, 0, stream>>>(
        rp, fin, tmp5, strideR, z_v, NV);
  } else {
    // ---- fallback: push-atomic path ----
    float* wcu = (float*)d_ws;
    float* wcv = wcu + WDO;
    unsigned short* wtbu = (unsigned short*)(wcv + WDO);
    unsigned short* wtbv = wtbu + WDO;
    float* tmp = (float*)(wtbv + WDO);
    const int n4_out = out_size / 4;
    cumsum_w<<<(D_IN * O_OUT + 255) / 256, 256, 0, stream>>>(
        wu, wv, wcu, wcv, wtbu, wtbv);
    zero_f32<<<1024, 256, 0, stream>>>(out, n4_out);
    const int spmm_blocks = (E * 16 + 255) / 256;
    for (int r = 0; r < R_SUP; ++r) {
      const int* rws = sup_rows + (size_t)r * E;
      const int* cls = sup_cols + (size_t)r * E;
      const float* vls = sup_vals + (size_t)r * E;
      gemm64<<<(NV + 63) / 64, 256, 0, stream>>>(x_v, wcv + r * D_IN * O_OUT, tmp, NV);
      spmm_push<<<spmm_blocks, 256, 0, stream>>>(rws, cls, vls, tmp, z_u, E);
      gemm64<<<(NU + 63) / 64, 256, 0, stream>>>(x_u, wcu + r * D_IN * O_OUT, tmp, NU);
      spmm_push<<<spmm_blocks, 256, 0, stream>>>(cls, rws, vls, tmp, z_v, E);
    }
    relu_f32<<<1024, 256, 0, stream>>>(out, n4_out);
  }
}